// Round 1
// baseline (566.767 us; speedup 1.0000x reference)
//
#include <hip/hip_runtime.h>
#include <hip/hip_bf16.h>

typedef __hip_bfloat16 bf16;
typedef __attribute__((ext_vector_type(8))) short short8;
typedef __attribute__((ext_vector_type(4))) short short4v;
typedef __attribute__((ext_vector_type(4))) float float4v;

__device__ __forceinline__ short f2bs(float f){
    union { bf16 h; short s; } u; u.h = __float2bfloat16(f); return u.s;
}
__device__ __forceinline__ float bs2f(short s){
    return __uint_as_float(((unsigned)(unsigned short)s) << 16);
}
__device__ __forceinline__ float gelu_exact(float x){
    return 0.5f * x * (1.0f + erff(x * 0.70710678118654752440f));
}
__device__ __forceinline__ short8 load_w8(const float* p){
    float4v w0 = *(const float4v*)p;
    float4v w1 = *(const float4v*)(p + 4);
    short8 r;
    r[0]=f2bs(w0[0]); r[1]=f2bs(w0[1]); r[2]=f2bs(w0[2]); r[3]=f2bs(w0[3]);
    r[4]=f2bs(w1[0]); r[5]=f2bs(w1[1]); r[6]=f2bs(w1[2]); r[7]=f2bs(w1[3]);
    return r;
}
#define MFMA(a,b,c) __builtin_amdgcn_mfma_f32_16x16x32_bf16((a),(b),(c),0,0,0)

#define HW 16384
#define NPLANE 1048576
#define EPS 1e-5f
#define LS 72             // LDS row stride in bf16 (144 B)

// ---------------- Kernel 1: per-(b,c) LN1 stats over H*W ----------------
__global__ __launch_bounds__(256) void k_stats(const float* __restrict__ x,
                                               float* __restrict__ mu,
                                               float* __restrict__ rinv){
    int bc = blockIdx.x;
    const float* p = x + (size_t)bc * HW;
    float s = 0.f, ss = 0.f;
    for (int i = threadIdx.x; i < HW; i += 256){
        float v = p[i]; s += v; ss += v*v;
    }
    __shared__ float rs[256], rss[256];
    rs[threadIdx.x] = s; rss[threadIdx.x] = ss; __syncthreads();
    for (int st = 128; st > 0; st >>= 1){
        if (threadIdx.x < st){ rs[threadIdx.x] += rs[threadIdx.x+st]; rss[threadIdx.x] += rss[threadIdx.x+st]; }
        __syncthreads();
    }
    if (threadIdx.x == 0){
        float m = rs[0] * (1.f/HW);
        float v = rss[0] * (1.f/HW) - m*m;
        mu[bc] = m; rinv[bc] = rsqrtf(v + EPS);
    }
}

// ---------------- Kernel 2: LN1 + 1x1 conv, both branches (MFMA) ----------------
// br0 -> y1 planar fp32 (d_out, read in-place by k_attn)
// br1 -> w2g window-major fp32 ([b][win][t][c])
// both -> LN2 partial sums (atomicAdd into stat[sum:2048 | sumsq:2048])
__global__ __launch_bounds__(256) void k_conv(const float* __restrict__ x,
                                              const float* __restrict__ mu,
                                              const float* __restrict__ rinv,
                                              const float* __restrict__ g1a, const float* __restrict__ b1a,
                                              const float* __restrict__ w1,  const float* __restrict__ cb1,
                                              const float* __restrict__ g1b, const float* __restrict__ b1b,
                                              const float* __restrict__ w2,  const float* __restrict__ cb2,
                                              float* __restrict__ y1, float* __restrict__ w2g,
                                              float* __restrict__ stat){
    int blk = blockIdx.x;          // 16*256 blocks
    int b = blk >> 8; int tile = blk & 255; int hw0 = tile * 64;
    __shared__ __align__(16) short xn_bf[64*LS];
    __shared__ float rowsumS[2][64];
    const int tid = threadIdx.x;
    const int wq = tid >> 6, lane = tid & 63, qd = lane >> 4, col = lane & 15;
    const float4v zf = {0.f,0.f,0.f,0.f};

    for (int i = tid; i < 1024; i += 256){
        int c = i >> 4, p0 = (i & 15) * 4;
        int bc = b*64 + c;
        float m = mu[bc], rv = rinv[bc];
        float4v v = *(const float4v*)(x + (size_t)bc*HW + hw0 + p0);
        #pragma unroll
        for (int k = 0; k < 4; k++) xn_bf[(p0+k)*LS + c] = f2bs((v[k] - m) * rv);
    }
    if (tid < 128){
        int br = tid >> 6, o = tid & 63;
        const float* W = br ? w2 : w1;
        float s = 0.f;
        for (int c = 0; c < 64; c++) s += W[o*64 + c];
        rowsumS[br][o] = s;
    }
    __syncthreads();

    #pragma unroll
    for (int br = 0; br < 2; br++){
        const float* W  = br ? w2  : w1;
        const float* cb = br ? cb2 : cb1;
        const float* gp = br ? g1b : g1a;
        const float* bp = br ? b1b : b1a;
        short8 a0 = load_w8(W + (size_t)(16*wq + col)*64 + 8*qd);
        short8 a1 = load_w8(W + (size_t)(16*wq + col)*64 + 32 + 8*qd);
        float cbv[4], rsv[4];
        #pragma unroll
        for (int r = 0; r < 4; r++){
            int o = 16*wq + 4*qd + r;
            cbv[r] = cb[o]; rsv[r] = rowsumS[br][o];
        }
        float sa[4]  = {0.f,0.f,0.f,0.f};
        float ssa[4] = {0.f,0.f,0.f,0.f};
        #pragma unroll
        for (int jn = 0; jn < 4; jn++){
            short8 bx0 = *(const short8*)&xn_bf[(16*jn + col)*LS + 8*qd];
            short8 bx1 = *(const short8*)&xn_bf[(16*jn + col)*LS + 32 + 8*qd];
            float4v acc = zf;
            acc = MFMA(a0, bx0, acc);
            acc = MFMA(a1, bx1, acc);
            int hw = hw0 + 16*jn + col;
            float gl = gp[hw], bl = bp[hw];
            float vals[4];
            #pragma unroll
            for (int r = 0; r < 4; r++){
                vals[r] = gl*acc[r] + bl*rsv[r] + cbv[r];
                sa[r]  += vals[r];
                ssa[r] += vals[r]*vals[r];
            }
            if (br == 0){
                #pragma unroll
                for (int r = 0; r < 4; r++)
                    y1[(size_t)(b*64 + 16*wq + 4*qd + r)*HW + hw] = vals[r];
            } else {
                int row = hw >> 7, cc = hw & 127;
                int win = (row >> 3)*16 + (cc >> 3);
                int t   = (row & 7)*8 + (cc & 7);
                float4v vv;
                #pragma unroll
                for (int r = 0; r < 4; r++) vv[r] = vals[r];
                *(float4v*)(w2g + ((size_t)(b*256 + win)*64 + t)*64 + 16*wq + 4*qd) = vv;
            }
        }
        float* Ssum = stat + br*1024 + b*64;
        float* Ssq  = stat + 2048 + br*1024 + b*64;
        #pragma unroll
        for (int r = 0; r < 4; r++){
            float s = sa[r], ss = ssa[r];
            s += __shfl_xor(s, 1); ss += __shfl_xor(ss, 1);
            s += __shfl_xor(s, 2); ss += __shfl_xor(ss, 2);
            s += __shfl_xor(s, 4); ss += __shfl_xor(ss, 4);
            s += __shfl_xor(s, 8); ss += __shfl_xor(ss, 8);
            if (col == 0){
                atomicAdd(&Ssum[16*wq + 4*qd + r], s);
                atomicAdd(&Ssq [16*wq + 4*qd + r], ss);
            }
        }
    }
}

// ---------------- Kernel 3: finalize LN2 stats (2048 = 2 branches x 1024 bc) ----------------
__global__ __launch_bounds__(256) void k_fin(const float* __restrict__ S,
                                             const float* __restrict__ S2,
                                             float* __restrict__ mu2,
                                             float* __restrict__ rinv2){
    int i = blockIdx.x*256 + threadIdx.x;
    float m = S[i] * (1.f/HW);
    float v = S2[i] * (1.f/HW) - m*m;
    mu2[i] = m; rinv2[i] = rsqrtf(v + EPS);
}

// ---------------- Kernel 4: LN2+GELU on load + attention + LAM + proj + channel-MLP ----------------
// x1 = raw conv branch-1 (planar, d_out) -> final output written in place.
// w2g = raw conv branch-2 (window-major, ws).
// LDS: 4 x 9216 buffers + rpb = 40464 B -> 4 blocks/CU (was 3).
__global__ __launch_bounds__(256, 4) void k_attn(float* __restrict__ x1, const float* __restrict__ w2g,
                                              const float* __restrict__ mu2, const float* __restrict__ rinv2,
                                              const float* __restrict__ g2a, const float* __restrict__ b2a,
                                              const float* __restrict__ g2b, const float* __restrict__ b2b,
                                              const float* __restrict__ pos1, const float* __restrict__ pos2,
                                              const float* __restrict__ qw, const float* __restrict__ qb,
                                              const float* __restrict__ kvw, const float* __restrict__ kvb,
                                              const float* __restrict__ rpb, const float* __restrict__ gammap,
                                              const float* __restrict__ pw, const float* __restrict__ pb,
                                              const float* __restrict__ n2g, const float* __restrict__ n2b,
                                              const float* __restrict__ fw1, const float* __restrict__ fb1,
                                              const float* __restrict__ fw2, const float* __restrict__ fb2){
    // XCD swizzle (unchanged from prior session)
    int B = blockIdx.x;
    int hy = (B & 7) | ((B >> 5) & 8);
    int wx = (((B >> 9) & 7) << 1) | ((B >> 3) & 1);
    int b  = (B >> 4) & 15;
    int win = hy*16 + wx;

    __shared__ __align__(16) char smem[40464];
    short* bufA = (short*)smem;                    // X2w -> X1w -> P (per head)
    short* bufK = (short*)(smem + 9216);           // K -> Y[t][c]
    short* bufV = (short*)(smem + 18432);          // VT -> OT[c][t]
    short* bufQ = (short*)(smem + 27648);          // Q -> XO -> h1
    float* rpb_lds = (float*)(smem + 36864);       // 3600 (dead after head loop)
    float* energyS = (float*)(smem + 36864);       // 1024, aliases rpb
    short* soft_bf = (short*)(smem + 37888);       // 1024, aliases rpb
    // MLP-tail aliases:
    float* XOf  = (float*)smem;                    // 64x65 fp32 over bufA+bufK
    float* sumS = (float*)(smem + 18432);          // 4x64 (bufV, dead after energy)
    float* sqS  = (float*)(smem + 19456);          // 4x64
    float* muS  = (float*)(smem + 36864);          // 64 (energy dead)
    float* rinvS= (float*)(smem + 37120);          // 64
    short* tnb  = (short*)(smem + 18432);          // tn bf16 over bufV (sums dead)
    short* h1b  = (short*)(smem + 27648);          // h1 over bufQ (XO dead)

    const int tid = threadIdx.x;
    const int wq = tid >> 6, lane = tid & 63, qd = lane >> 4, col = lane & 15;
    size_t base = (size_t)b * NPLANE;
    #define HWOF(t) ((hy*8 + ((t)>>3))*128 + wx*8 + ((t)&7))

    const float4v zf = {0.f,0.f,0.f,0.f};
    const short8 zero8 = {0,0,0,0,0,0,0,0};

    for (int i = tid; i < 900; i += 256) rpb_lds[i] = rpb[i];

    // ---- load X2 window (contiguous) + LN2b + GELU + pos2 -> bufA ----
    {
        const float* src = w2g + ((size_t)(b*256 + win) << 12);
        int t = tid >> 2, c0 = (tid & 3) << 4;
        int hw = HWOF(t);
        float g = g2b[hw], lb = b2b[hw];
        const float* mup = mu2   + 1024 + b*64 + c0;
        const float* rvp = rinv2 + 1024 + b*64 + c0;
        short8 o8[2];
        #pragma unroll
        for (int k = 0; k < 4; k++){
            float4v v  = *(const float4v*)(src + (size_t)t*64 + c0 + 4*k);
            float4v m4 = *(const float4v*)(mup + 4*k);
            float4v r4 = *(const float4v*)(rvp + 4*k);
            float4v p4 = *(const float4v*)(pos2 + t*64 + c0 + 4*k);
            #pragma unroll
            for (int j = 0; j < 4; j++){
                float z = (v[j] - m4[j]) * r4[j] * g + lb;
                o8[k>>1][(k&1)*4 + j] = f2bs(gelu_exact(z) + p4[j]);
            }
        }
        *(short8*)&bufA[t*LS + c0]     = o8[0];
        *(short8*)&bufA[t*LS + c0 + 8] = o8[1];
    }
    __syncthreads();

    // ---- VT = Wv · X2^T ----
    {
        float bvr[4];
        #pragma unroll
        for (int r = 0; r < 4; r++) bvr[r] = kvb[64 + 16*wq + 4*qd + r];
        short8 a0 = load_w8(kvw + (size_t)(64 + 16*wq + col)*64 + 8*qd);
        short8 a1 = load_w8(kvw + (size_t)(64 + 16*wq + col)*64 + 32 + 8*qd);
        #pragma unroll
        for (int jn = 0; jn < 4; jn++){
            int u = 16*jn + col;
            short8 b0 = *(const short8*)&bufA[u*LS + 8*qd];
            short8 b1 = *(const short8*)&bufA[u*LS + 32 + 8*qd];
            float4v acc = zf;
            acc = MFMA(a0, b0, acc);
            acc = MFMA(a1, b1, acc);
            #pragma unroll
            for (int r = 0; r < 4; r++)
                bufV[(16*wq + 4*qd + r)*LS + u] = f2bs(acc[r] + bvr[r]);
        }
    }
    // ---- K = X2 · Wk^T ----
    {
        short8 ax0 = *(const short8*)&bufA[(16*wq + col)*LS + 8*qd];
        short8 ax1 = *(const short8*)&bufA[(16*wq + col)*LS + 32 + 8*qd];
        #pragma unroll
        for (int jn = 0; jn < 4; jn++){
            int co = 16*jn + col;
            short8 b0 = load_w8(kvw + (size_t)co*64 + 8*qd);
            short8 b1 = load_w8(kvw + (size_t)co*64 + 32 + 8*qd);
            float4v acc = zf;
            acc = MFMA(ax0, b0, acc);
            acc = MFMA(ax1, b1, acc);
            float kb = kvb[co];
            #pragma unroll
            for (int r = 0; r < 4; r++)
                bufK[(16*wq + 4*qd + r)*LS + co] = f2bs(acc[r] + kb);
        }
    }
    __syncthreads();

    // ---- load X1 (planar raw conv out) + LN2a + GELU + pos1 -> bufA ----
    for (int i = tid; i < 1024; i += 256){
        int c = i >> 4, t0 = (i & 15) * 4;
        int bc = b*64 + c;
        float m = mu2[bc], rv = rinv2[bc];
        int hw = HWOF(t0);
        float4v v  = *(const float4v*)(x1 + base + (size_t)c*HW + hw);
        float4v g4 = *(const float4v*)(g2a + hw);
        float4v b4 = *(const float4v*)(b2a + hw);
        #pragma unroll
        for (int k = 0; k < 4; k++){
            float z = (v[k] - m) * rv * g4[k] + b4[k];
            bufA[(t0+k)*LS + c] = f2bs(gelu_exact(z) + pos1[(t0+k)*64 + c]);
        }
    }
    __syncthreads();

    // ---- Q = 0.25 * (X1 · Wq^T + qb); keep per-thread fragment in regs ----
    short4v qreg[4];
    {
        short8 ax0 = *(const short8*)&bufA[(16*wq + col)*LS + 8*qd];
        short8 ax1 = *(const short8*)&bufA[(16*wq + col)*LS + 32 + 8*qd];
        #pragma unroll
        for (int jn = 0; jn < 4; jn++){
            int co = 16*jn + col;
            short8 b0 = load_w8(qw + (size_t)co*64 + 8*qd);
            short8 b1 = load_w8(qw + (size_t)co*64 + 32 + 8*qd);
            float4v acc = zf;
            acc = MFMA(ax0, b0, acc);
            acc = MFMA(ax1, b1, acc);
            float qbv = qb[co];
            short4v qv;
            #pragma unroll
            for (int r = 0; r < 4; r++){
                short s = f2bs((acc[r] + qbv) * 0.25f);
                qv[r] = s;
                bufQ[(16*wq + 4*qd + r)*LS + co] = s;
            }
            qreg[jn] = qv;
        }
    }
    __syncthreads();

    // ---- capture X1w values needed at XO-assembly, then free bufA for P ----
    short4v xreg[4];
    #pragma unroll
    for (int h = 0; h < 4; h++){
        short4v xr;
        #pragma unroll
        for (int r = 0; r < 4; r++)
            xr[r] = bufA[(16*wq + 4*qd + r)*LS + 16*h + col];
        xreg[h] = xr;
    }
    __syncthreads();

    int idx_t[4][4];
    #pragma unroll
    for (int jn = 0; jn < 4; jn++){
        int u = 16*jn + col; int uy = u >> 3, ux = u & 7;
        #pragma unroll
        for (int r = 0; r < 4; r++){
            int t = 16*wq + 4*qd + r;
            idx_t[jn][r] = ((t>>3) - uy + 7)*15 + ((t&7) - ux + 7);
        }
    }

    // ---- head loop: S -> softmax -> P (bufA) -> PV -> OT/Y ----
    for (int h = 0; h < 4; h++){
        short8 aq = *(const short8*)&bufQ[(16*wq + col)*LS + h*16 + (qd & 1)*8];
        if (qd >= 2) aq = zero8;
        float4v acc_s[4];
        #pragma unroll
        for (int jn = 0; jn < 4; jn++){
            int u = 16*jn + col;
            short8 bk = *(const short8*)&bufK[u*LS + h*16 + (qd & 1)*8];
            acc_s[jn] = MFMA(aq, bk, zf);
        }
        float pr[4][4];
        #pragma unroll
        for (int jn = 0; jn < 4; jn++)
            #pragma unroll
            for (int r = 0; r < 4; r++)
                pr[jn][r] = acc_s[jn][r] + rpb_lds[idx_t[jn][r]*4 + h];
        #pragma unroll
        for (int r = 0; r < 4; r++){
            float m = fmaxf(fmaxf(pr[0][r], pr[1][r]), fmaxf(pr[2][r], pr[3][r]));
            m = fmaxf(m, __shfl_xor(m, 1)); m = fmaxf(m, __shfl_xor(m, 2));
            m = fmaxf(m, __shfl_xor(m, 4)); m = fmaxf(m, __shfl_xor(m, 8));
            float s = 0.f;
            #pragma unroll
            for (int jn = 0; jn < 4; jn++){ pr[jn][r] = __expf(pr[jn][r] - m); s += pr[jn][r]; }
            s += __shfl_xor(s, 1); s += __shfl_xor(s, 2);
            s += __shfl_xor(s, 4); s += __shfl_xor(s, 8);
            float rc = 1.f / s;
            #pragma unroll
            for (int jn = 0; jn < 4; jn++)
                bufA[(16*wq + 4*qd + r)*LS + 16*jn + col] = f2bs(pr[jn][r] * rc);
        }
        __syncthreads();
        short8 ap0 = *(const short8*)&bufA[(16*wq + col)*LS + 8*qd];
        short8 ap1 = *(const short8*)&bufA[(16*wq + col)*LS + 32 + 8*qd];
        short8 bv0 = *(const short8*)&bufV[(h*16 + col)*LS + 8*qd];
        short8 bv1 = *(const short8*)&bufV[(h*16 + col)*LS + 32 + 8*qd];
        float4v acc_o = zf;
        acc_o = MFMA(ap0, bv0, acc_o);
        acc_o = MFMA(ap1, bv1, acc_o);
        __syncthreads();
        short4v ot;
        #pragma unroll
        for (int r = 0; r < 4; r++) ot[r] = f2bs(acc_o[r]);
        *(short4v*)&bufV[(h*16 + col)*LS + 16*wq + 4*qd] = ot;
        #pragma unroll
        for (int r = 0; r < 4; r++)
            bufK[(16*wq + 4*qd + r)*LS + h*16 + col] = ot[r];
    }
    __syncthreads();

    // ---- energy = Y Y^T (16x16, K=256) ----
    {
        float4v acc_e = zf;
        #pragma unroll
        for (int h = 0; h < 4; h++){
            short8 f0 = *(const short8*)&bufV[(h*16 + col)*LS + 8*qd];
            short8 f1 = *(const short8*)&bufV[(h*16 + col)*LS + 32 + 8*qd];
            acc_e = MFMA(f0, f0, acc_e);
            acc_e = MFMA(f1, f1, acc_e);
        }
        if (wq == 0){
            #pragma unroll
            for (int r = 0; r < 4; r++) energyS[(4*qd + r)*16 + col] = acc_e[r];
        }
    }
    __syncthreads();
    if (tid < 16){
        int i = tid; float m = -1e30f;
        for (int j = 0; j < 16; j++) m = fmaxf(m, energyS[i*16 + j]);
        float s = 0.f; float e[16];
        for (int j = 0; j < 16; j++){ e[j] = __expf(energyS[i*16 + j] - m); s += e[j]; }
        float rc = 1.f / s;
        for (int j = 0; j < 16; j++) soft_bf[i*32 + j] = f2bs(e[j] * rc);
        for (int j = 0; j < 16; j++) soft_bf[i*32 + 16 + j] = 0;
    }
    __syncthreads();

    // ---- lam^T + assemble XO -> bufQ ----
    // C[t][d] = sum_{d'} Y[t][16h+d'] * soft[d][d']  (zeros come from soft rows>=16)
    {
        float gam = gammap[0];
        short8 asf = *(const short8*)&soft_bf[col*32 + 8*qd];
        #pragma unroll
        for (int h = 0; h < 4; h++){
            short8 ay = *(const short8*)&bufK[(16*wq + col)*LS + 16*h + (qd & 1)*8];
            float4v acc = MFMA(ay, asf, zf);
            short4v qv = qreg[h], xv = xreg[h];
            #pragma unroll
            for (int r = 0; r < 4; r++){
                float ot = bs2f(bufK[(16*wq + 4*qd + r)*LS + 16*h + col]);
                float xo = gam*acc[r] + ot + bs2f(qv[r]) + bs2f(xv[r]);
                bufQ[(16*wq + 4*qd + r)*LS + 16*h + col] = f2bs(xo);
            }
        }
    }
    __syncthreads();

    // ---- proj: XO · Wp^T + pb -> XOf (fp32 LDS over bufA+bufK) ----
    {
        short8 a0 = *(const short8*)&bufQ[(16*wq + col)*LS + 8*qd];
        short8 a1 = *(const short8*)&bufQ[(16*wq + col)*LS + 32 + 8*qd];
        #pragma unroll
        for (int jn = 0; jn < 4; jn++){
            int c = 16*jn + col;
            short8 b0 = load_w8(pw + (size_t)c*64 + 8*qd);
            short8 b1 = load_w8(pw + (size_t)c*64 + 32 + 8*qd);
            float4v acc = zf;
            acc = MFMA(a0, b0, acc);
            acc = MFMA(a1, b1, acc);
            float pbv = pb[c];
            #pragma unroll
            for (int r = 0; r < 4; r++)
                XOf[(16*wq + 4*qd + r)*65 + c] = acc[r] + pbv;
        }
    }
    __syncthreads();

    // ================= fused channel-MLP =================
    {
        int p = tid & 63, qg = tid >> 6;
        float s = 0.f, ss = 0.f;
        #pragma unroll
        for (int j = 0; j < 16; j++){ float v = XOf[p*65 + qg*16 + j]; s += v; ss += v*v; }
        sumS[qg*64 + p] = s; sqS[qg*64 + p] = ss;
    }
    __syncthreads();
    if (tid < 64){
        float s  = sumS[tid] + sumS[64+tid] + sumS[128+tid] + sumS[192+tid];
        float ss = sqS[tid]  + sqS[64+tid]  + sqS[128+tid]  + sqS[192+tid];
        float m = s * (1.f/64.f);
        float var = ss * (1.f/64.f) - m*m;
        muS[tid] = m; rinvS[tid] = rsqrtf(var + EPS);
    }
    __syncthreads();
    // tn -> tnb (bf16, over bufV)
    {
        int p = tid & 63, qg = tid >> 6;
        float m = muS[p], rv = rinvS[p];
        #pragma unroll
        for (int j = 0; j < 16; j++){
            int c = qg*16 + j;
            tnb[p*LS + c] = f2bs((XOf[p*65 + c] - m) * rv * n2g[c] + n2b[c]);
        }
    }
    __syncthreads();
    // GEMM1: h1 = gelu(tn @ W1^T + fb1) -> h1b (over bufQ)
    {
        short8 a0 = *(const short8*)&tnb[(16*wq + col)*LS + 8*qd];
        short8 a1 = *(const short8*)&tnb[(16*wq + col)*LS + 32 + 8*qd];
        #pragma unroll
        for (int jn = 0; jn < 4; jn++){
            int j = 16*jn + col;
            short8 f0 = load_w8(fw1 + (size_t)j*64 + 8*qd);
            short8 f1 = load_w8(fw1 + (size_t)j*64 + 32 + 8*qd);
            float4v acc = zf;
            acc = MFMA(a0, f0, acc);
            acc = MFMA(a1, f1, acc);
            float bv = fb1[j];
            #pragma unroll
            for (int r = 0; r < 4; r++)
                h1b[(16*wq + 4*qd + r)*LS + j] = f2bs(gelu_exact(acc[r] + bv));
        }
    }
    __syncthreads();
    // GEMM2: out = xo + h1 @ W2^T + fb2 -> global (in place over x1)
    {
        short8 a0 = *(const short8*)&h1b[(16*wq + col)*LS + 8*qd];
        short8 a1 = *(const short8*)&h1b[(16*wq + col)*LS + 32 + 8*qd];
        #pragma unroll
        for (int jn = 0; jn < 4; jn++){
            int c2 = 16*jn + col;
            short8 f0 = load_w8(fw2 + (size_t)c2*64 + 8*qd);
            short8 f1 = load_w8(fw2 + (size_t)c2*64 + 32 + 8*qd);
            float4v acc = zf;
            acc = MFMA(a0, f0, acc);
            acc = MFMA(a1, f1, acc);
            float bv = fb2[c2];
            float4v ov;
            #pragma unroll
            for (int r = 0; r < 4; r++)
                ov[r] = acc[r] + bv + XOf[(16*wq + 4*qd + r)*65 + c2];
            int t0 = 16*wq + 4*qd;
            *(float4v*)(x1 + base + (size_t)c2*HW + HWOF(t0)) = ov;
        }
    }
    #undef HWOF
}

extern "C" void kernel_launch(void* const* d_in, const int* in_sizes, int n_in,
                              void* d_out, int out_size, void* d_ws, size_t ws_size,
                              hipStream_t stream){
    const float* x        = (const float*)d_in[0];
    const float* l1_g1    = (const float*)d_in[1];
    const float* l1_b1    = (const float*)d_in[2];
    const float* l1_cw    = (const float*)d_in[3];
    const float* l1_cb    = (const float*)d_in[4];
    const float* l1_g2    = (const float*)d_in[5];
    const float* l1_b2    = (const float*)d_in[6];
    const float* l2_g1    = (const float*)d_in[7];
    const float* l2_b1    = (const float*)d_in[8];
    const float* l2_cw    = (const float*)d_in[9];
    const float* l2_cb    = (const float*)d_in[10];
    const float* l2_g2    = (const float*)d_in[11];
    const float* l2_b2    = (const float*)d_in[12];
    const float* pos1     = (const float*)d_in[13];
    const float* pos2     = (const float*)d_in[14];
    const float* q_w      = (const float*)d_in[15];
    const float* q_b      = (const float*)d_in[16];
    const float* kv_w     = (const float*)d_in[17];
    const float* kv_b     = (const float*)d_in[18];
    const float* rpb      = (const float*)d_in[19];
    const float* gamma    = (const float*)d_in[20];
    const float* proj_w   = (const float*)d_in[21];
    const float* proj_b   = (const float*)d_in[22];
    const float* norm2_g  = (const float*)d_in[23];
    const float* norm2_b  = (const float*)d_in[24];
    const float* fc1_w    = (const float*)d_in[25];
    const float* fc1_b    = (const float*)d_in[26];
    const float* fc2_w    = (const float*)d_in[27];
    const float* fc2_b    = (const float*)d_in[28];

    float* out = (float*)d_out;                 // branch-1 conv out -> final, in place

    float* w2g   = (float*)d_ws;                // 16*NPLANE floats (67 MB), window-major branch-2
    float* stat  = w2g + (size_t)16*NPLANE;     // 4096: [sum br0|br1 | sumsq br0|br1]
    float* mu1   = stat + 4096;                 // 1024
    float* rinv1 = mu1 + 1024;                  // 1024
    float* mu2   = rinv1 + 1024;                // 2048
    float* rinv2 = mu2 + 2048;                  // 2048

    k_stats<<<1024, 256, 0, stream>>>(x, mu1, rinv1);
    hipMemsetAsync(stat, 0, 4096*sizeof(float), stream);
    k_conv <<<4096, 256, 0, stream>>>(x, mu1, rinv1,
                                      l1_g1, l1_b1, l1_cw, l1_cb,
                                      l2_g1, l2_b1, l2_cw, l2_cb,
                                      out, w2g, stat);
    k_fin  <<<8, 256, 0, stream>>>(stat, stat + 2048, mu2, rinv2);
    k_attn <<<4096, 256, 0, stream>>>(out, w2g, mu2, rinv2,
                                      l1_g2, l1_b2, l2_g2, l2_b2,
                                      pos1, pos2, q_w, q_b, kv_w, kv_b,
                                      rpb, gamma, proj_w, proj_b,
                                      norm2_g, norm2_b, fc1_w, fc1_b, fc2_w, fc2_b);
}

// Round 2
// 419.677 us; speedup vs baseline: 1.3505x; 1.3505x over previous
//
#include <hip/hip_runtime.h>
#include <hip/hip_bf16.h>

typedef __hip_bfloat16 bf16;
typedef __attribute__((ext_vector_type(8))) short short8;
typedef __attribute__((ext_vector_type(4))) short short4v;
typedef __attribute__((ext_vector_type(4))) float float4v;
typedef __attribute__((ext_vector_type(2))) float float2v;

__device__ __forceinline__ short f2bs(float f){
    union { bf16 h; short s; } u; u.h = __float2bfloat16(f); return u.s;
}
__device__ __forceinline__ float bs2f(short s){
    return __uint_as_float(((unsigned)(unsigned short)s) << 16);
}
__device__ __forceinline__ float gelu_exact(float x){
    return 0.5f * x * (1.0f + erff(x * 0.70710678118654752440f));
}
__device__ __forceinline__ short8 load_w8(const float* p){
    float4v w0 = *(const float4v*)p;
    float4v w1 = *(const float4v*)(p + 4);
    short8 r;
    r[0]=f2bs(w0[0]); r[1]=f2bs(w0[1]); r[2]=f2bs(w0[2]); r[3]=f2bs(w0[3]);
    r[4]=f2bs(w1[0]); r[5]=f2bs(w1[1]); r[6]=f2bs(w1[2]); r[7]=f2bs(w1[3]);
    return r;
}
#define MFMA(a,b,c) __builtin_amdgcn_mfma_f32_16x16x32_bf16((a),(b),(c),0,0,0)

#define HW 16384
#define NPLANE 1048576
#define EPS 1e-5f
#define LS 72             // LDS row stride in bf16 (144 B)

// ---------------- Kernel 1: per-(b,c) LN1 stats over H*W ----------------
__global__ __launch_bounds__(256) void k_stats(const float* __restrict__ x,
                                               float* __restrict__ mu,
                                               float* __restrict__ rinv){
    int bc = blockIdx.x;
    const float* p = x + (size_t)bc * HW;
    float s = 0.f, ss = 0.f;
    for (int i = threadIdx.x; i < HW/4; i += 256){
        float4v v = *(const float4v*)(p + i*4);
        #pragma unroll
        for (int k = 0; k < 4; k++){ s += v[k]; ss += v[k]*v[k]; }
    }
    __shared__ float rs[256], rss[256];
    rs[threadIdx.x] = s; rss[threadIdx.x] = ss; __syncthreads();
    for (int st = 128; st > 0; st >>= 1){
        if (threadIdx.x < st){ rs[threadIdx.x] += rs[threadIdx.x+st]; rss[threadIdx.x] += rss[threadIdx.x+st]; }
        __syncthreads();
    }
    if (threadIdx.x == 0){
        float m = rs[0] * (1.f/HW);
        float v = rss[0] * (1.f/HW) - m*m;
        mu[bc] = m; rinv[bc] = rsqrtf(v + EPS);
    }
}

// ---------------- Kernel 2: LN1 + 1x1 conv, both branches (MFMA) ----------------
// br0 -> y1 planar fp32 (d_out); br1 -> w2g window-major fp32 ([b][win][t][c])
// LN2 partials -> partS/partQ [br][b][o][tile] (no atomics)
__global__ __launch_bounds__(256) void k_conv(const float* __restrict__ x,
                                              const float* __restrict__ mu,
                                              const float* __restrict__ rinv,
                                              const float* __restrict__ g1a, const float* __restrict__ b1a,
                                              const float* __restrict__ w1,  const float* __restrict__ cb1,
                                              const float* __restrict__ g1b, const float* __restrict__ b1b,
                                              const float* __restrict__ w2,  const float* __restrict__ cb2,
                                              float* __restrict__ y1, float* __restrict__ w2g,
                                              float* __restrict__ partS, float* __restrict__ partQ){
    int blk = blockIdx.x;          // 16*256 blocks
    int b = blk >> 8; int tile = blk & 255; int hw0 = tile * 64;
    __shared__ __align__(16) short xn_bf[64*LS];
    __shared__ float rowsumS[2][64];
    const int tid = threadIdx.x;
    const int wq = tid >> 6, lane = tid & 63, qd = lane >> 4, col = lane & 15;
    const float4v zf = {0.f,0.f,0.f,0.f};

    for (int i = tid; i < 1024; i += 256){
        int c = i >> 4, p0 = (i & 15) * 4;
        int bc = b*64 + c;
        float m = mu[bc], rv = rinv[bc];
        float4v v = *(const float4v*)(x + (size_t)bc*HW + hw0 + p0);
        #pragma unroll
        for (int k = 0; k < 4; k++) xn_bf[(p0+k)*LS + c] = f2bs((v[k] - m) * rv);
    }
    if (tid < 128){
        int br = tid >> 6, o = tid & 63;
        const float* W = br ? w2 : w1;
        float s = 0.f;
        for (int c = 0; c < 64; c++) s += W[o*64 + c];
        rowsumS[br][o] = s;
    }
    __syncthreads();

    #pragma unroll
    for (int br = 0; br < 2; br++){
        const float* W  = br ? w2  : w1;
        const float* cb = br ? cb2 : cb1;
        const float* gp = br ? g1b : g1a;
        const float* bp = br ? b1b : b1a;
        short8 a0 = load_w8(W + (size_t)(16*wq + col)*64 + 8*qd);
        short8 a1 = load_w8(W + (size_t)(16*wq + col)*64 + 32 + 8*qd);
        float cbv[4], rsv[4];
        #pragma unroll
        for (int r = 0; r < 4; r++){
            int o = 16*wq + 4*qd + r;
            cbv[r] = cb[o]; rsv[r] = rowsumS[br][o];
        }
        float sa[4]  = {0.f,0.f,0.f,0.f};
        float ssa[4] = {0.f,0.f,0.f,0.f};
        #pragma unroll
        for (int jn = 0; jn < 4; jn++){
            short8 bx0 = *(const short8*)&xn_bf[(16*jn + col)*LS + 8*qd];
            short8 bx1 = *(const short8*)&xn_bf[(16*jn + col)*LS + 32 + 8*qd];
            float4v acc = zf;
            acc = MFMA(a0, bx0, acc);
            acc = MFMA(a1, bx1, acc);
            int hw = hw0 + 16*jn + col;
            float gl = gp[hw], bl = bp[hw];
            float vals[4];
            #pragma unroll
            for (int r = 0; r < 4; r++){
                vals[r] = gl*acc[r] + bl*rsv[r] + cbv[r];
                sa[r]  += vals[r];
                ssa[r] += vals[r]*vals[r];
            }
            if (br == 0){
                #pragma unroll
                for (int r = 0; r < 4; r++)
                    y1[(size_t)(b*64 + 16*wq + 4*qd + r)*HW + hw] = vals[r];
            } else {
                int row = hw >> 7, cc = hw & 127;
                int win = (row >> 3)*16 + (cc >> 3);
                int t   = (row & 7)*8 + (cc & 7);
                float4v vv;
                #pragma unroll
                for (int r = 0; r < 4; r++) vv[r] = vals[r];
                *(float4v*)(w2g + ((size_t)(b*256 + win)*64 + t)*64 + 16*wq + 4*qd) = vv;
            }
        }
        #pragma unroll
        for (int r = 0; r < 4; r++){
            float s = sa[r], ss = ssa[r];
            s += __shfl_xor(s, 1); ss += __shfl_xor(ss, 1);
            s += __shfl_xor(s, 2); ss += __shfl_xor(ss, 2);
            s += __shfl_xor(s, 4); ss += __shfl_xor(ss, 4);
            s += __shfl_xor(s, 8); ss += __shfl_xor(ss, 8);
            if (col == 0){
                int o = 16*wq + 4*qd + r;
                size_t pi = ((size_t)(br*16 + b)*64 + o)*256 + tile;
                partS[pi] = s; partQ[pi] = ss;
            }
        }
    }
}

// ---------------- Kernel 3: reduce LN2 partials (2048 rows x 256 tiles) ----------------
__global__ __launch_bounds__(256) void k_fin(const float* __restrict__ partS,
                                             const float* __restrict__ partQ,
                                             float* __restrict__ mu2,
                                             float* __restrict__ rinv2){
    int i = blockIdx.x*256 + threadIdx.x;    // br*1024 + b*64 + o
    const float* ps = partS + (size_t)i*256;
    const float* pq = partQ + (size_t)i*256;
    float s = 0.f, ss = 0.f;
    for (int k = 0; k < 64; k++){
        float4v a = *(const float4v*)(ps + k*4);
        float4v b = *(const float4v*)(pq + k*4);
        s += a[0]+a[1]+a[2]+a[3];
        ss += b[0]+b[1]+b[2]+b[3];
    }
    float m = s * (1.f/HW);
    float v = ss * (1.f/HW) - m*m;
    mu2[i] = m; rinv2[i] = rsqrtf(v + EPS);
}

// ---------------- Kernel 4: LN2+GELU on load + attention + LAM + proj + channel-MLP ----------------
// All MFMA write-backs packed (b64) via operand-role choice; S computed transposed so
// softmax rows are thread-local (2 shfls instead of 32 per head).
__global__ __launch_bounds__(256, 4) void k_attn(float* __restrict__ x1, const float* __restrict__ w2g,
                                              const float* __restrict__ mu2, const float* __restrict__ rinv2,
                                              const float* __restrict__ g2a, const float* __restrict__ b2a,
                                              const float* __restrict__ g2b, const float* __restrict__ b2b,
                                              const float* __restrict__ pos1, const float* __restrict__ pos2,
                                              const float* __restrict__ qw, const float* __restrict__ qb,
                                              const float* __restrict__ kvw, const float* __restrict__ kvb,
                                              const float* __restrict__ rpb, const float* __restrict__ gammap,
                                              const float* __restrict__ pw, const float* __restrict__ pb,
                                              const float* __restrict__ n2g, const float* __restrict__ n2b,
                                              const float* __restrict__ fw1, const float* __restrict__ fb1,
                                              const float* __restrict__ fw2, const float* __restrict__ fb2){
    int B = blockIdx.x;
    int hy = (B & 7) | ((B >> 5) & 8);
    int wx = (((B >> 9) & 7) << 1) | ((B >> 3) & 1);
    int b  = (B >> 4) & 15;
    int win = hy*16 + wx;

    __shared__ __align__(16) char smem[40464];
    short* bufA = (short*)smem;                    // X2w -> X1w -> P (wave-private)
    short* bufK = (short*)(smem + 9216);           // K -> Y[t][c] -> XO[t][c]
    short* bufV = (short*)(smem + 18432);          // V^T[c][t] -> Y^T[c][t]
    short* bufQ = (short*)(smem + 27648);          // Q[t][c]
    float* rpb_lds = (float*)(smem + 36864);       // 3600 (dead after head loop)
    float* energyS = (float*)(smem + 36864);       // 1024, aliases rpb
    short* soft_bf = (short*)(smem + 37888);       // 1024, aliases rpb
    // tail aliases:
    float* XOf  = (float*)(smem + 18432);          // 64x66 fp32 (16896 B) over bufV+bufQ
    short* tnb  = (short*)smem;                    // tn bf16 over bufA
    short* h1b  = (short*)(smem + 9216);           // h1 over bufK
    float* sumS = (float*)(smem + 36864);          // 1024
    float* sqS  = (float*)(smem + 37888);          // 1024
    float* muS  = (float*)(smem + 38912);          // 256
    float* rinvS= (float*)(smem + 39168);          // 256

    const int tid = threadIdx.x;
    const int wq = tid >> 6, lane = tid & 63, qd = lane >> 4, col = lane & 15;
    size_t base = (size_t)b * NPLANE;
    #define HWOF(t) ((hy*8 + ((t)>>3))*128 + wx*8 + ((t)&7))

    const float4v zf = {0.f,0.f,0.f,0.f};
    const short8 zero8 = {0,0,0,0,0,0,0,0};

    for (int i = tid; i < 900; i += 256) rpb_lds[i] = rpb[i];

    // ---- load X2 window (contiguous w2g) + LN2b + GELU + pos2 -> bufA [t][c] ----
    {
        const float* src = w2g + ((size_t)(b*256 + win) << 12);
        int t = tid >> 2, c0 = (tid & 3) << 4;
        int hw = HWOF(t);
        float g = g2b[hw], lb = b2b[hw];
        const float* mup = mu2   + 1024 + b*64 + c0;
        const float* rvp = rinv2 + 1024 + b*64 + c0;
        short8 o8[2];
        #pragma unroll
        for (int k = 0; k < 4; k++){
            float4v v  = *(const float4v*)(src + (size_t)t*64 + c0 + 4*k);
            float4v m4 = *(const float4v*)(mup + 4*k);
            float4v r4 = *(const float4v*)(rvp + 4*k);
            float4v p4 = *(const float4v*)(pos2 + t*64 + c0 + 4*k);
            #pragma unroll
            for (int j = 0; j < 4; j++){
                float z = (v[j] - m4[j]) * r4[j] * g + lb;
                o8[k>>1][(k&1)*4 + j] = f2bs(gelu_exact(z) + p4[j]);
            }
        }
        *(short8*)&bufA[t*LS + c0]     = o8[0];
        *(short8*)&bufA[t*LS + c0 + 8] = o8[1];
    }
    __syncthreads();

    // ---- V^T and K, both with packed b64 write-backs ----
    {
        // shared A-operand: X2 rows t = 16wq+col
        short8 ax0 = *(const short8*)&bufA[(16*wq + col)*LS + 8*qd];
        short8 ax1 = *(const short8*)&bufA[(16*wq + col)*LS + 32 + 8*qd];
        // V^T: A = X rows t, B = Wv rows c -> C[t][c]; write bufV[c][t] packed
        #pragma unroll
        for (int jn = 0; jn < 4; jn++){
            int c = 16*jn + col;
            short8 wv0 = load_w8(kvw + (size_t)(64 + c)*64 + 8*qd);
            short8 wv1 = load_w8(kvw + (size_t)(64 + c)*64 + 32 + 8*qd);
            float4v acc = zf;
            acc = MFMA(ax0, wv0, acc);
            acc = MFMA(ax1, wv1, acc);
            float bv = kvb[64 + c];
            short4v pk;
            #pragma unroll
            for (int r = 0; r < 4; r++) pk[r] = f2bs(acc[r] + bv);
            *(short4v*)&bufV[c*LS + 16*wq + 4*qd] = pk;
        }
        // K: A = Wk rows c (16wq block), B = X rows t -> C[c][t]; write bufK[t][c] packed
        short8 a0 = load_w8(kvw + (size_t)(16*wq + col)*64 + 8*qd);
        short8 a1 = load_w8(kvw + (size_t)(16*wq + col)*64 + 32 + 8*qd);
        float kbr[4];
        #pragma unroll
        for (int r = 0; r < 4; r++) kbr[r] = kvb[16*wq + 4*qd + r];
        #pragma unroll
        for (int jn = 0; jn < 4; jn++){
            int t = 16*jn + col;
            short8 bx0 = *(const short8*)&bufA[t*LS + 8*qd];
            short8 bx1 = *(const short8*)&bufA[t*LS + 32 + 8*qd];
            float4v acc = zf;
            acc = MFMA(a0, bx0, acc);
            acc = MFMA(a1, bx1, acc);
            short4v pk;
            #pragma unroll
            for (int r = 0; r < 4; r++) pk[r] = f2bs(acc[r] + kbr[r]);
            *(short4v*)&bufK[t*LS + 16*wq + 4*qd] = pk;
        }
    }
    __syncthreads();

    // ---- load X1 (planar) + LN2a + GELU + pos1 -> bufA [t][c] ----
    for (int i = tid; i < 1024; i += 256){
        int c = i >> 4, t0 = (i & 15) * 4;
        int bc = b*64 + c;
        float m = mu2[bc], rv = rinv2[bc];
        int hw = HWOF(t0);
        float4v v  = *(const float4v*)(x1 + base + (size_t)c*HW + hw);
        float4v g4 = *(const float4v*)(g2a + hw);
        float4v b4 = *(const float4v*)(b2a + hw);
        #pragma unroll
        for (int k = 0; k < 4; k++){
            float z = (v[k] - m) * rv * g4[k] + b4[k];
            bufA[(t0+k)*LS + c] = f2bs(gelu_exact(z) + pos1[(t0+k)*64 + c]);
        }
    }
    __syncthreads();

    // ---- Q: A = Wq rows c, B = X1 rows t -> C[c][t]; write bufQ[t][c] packed ----
    {
        short8 a0 = load_w8(qw + (size_t)(16*wq + col)*64 + 8*qd);
        short8 a1 = load_w8(qw + (size_t)(16*wq + col)*64 + 32 + 8*qd);
        float qbr[4];
        #pragma unroll
        for (int r = 0; r < 4; r++) qbr[r] = qb[16*wq + 4*qd + r];
        #pragma unroll
        for (int jn = 0; jn < 4; jn++){
            int t = 16*jn + col;
            short8 bx0 = *(const short8*)&bufA[t*LS + 8*qd];
            short8 bx1 = *(const short8*)&bufA[t*LS + 32 + 8*qd];
            float4v acc = zf;
            acc = MFMA(a0, bx0, acc);
            acc = MFMA(a1, bx1, acc);
            short4v pk;
            #pragma unroll
            for (int r = 0; r < 4; r++) pk[r] = f2bs((acc[r] + qbr[r]) * 0.25f);
            *(short4v*)&bufQ[t*LS + 16*wq + 4*qd] = pk;
        }
    }
    // capture X1w values needed at XO-assembly (own-wave rows), then bufA becomes P
    short4v xreg[4];
    #pragma unroll
    for (int h = 0; h < 4; h++){
        short4v xr;
        #pragma unroll
        for (int r = 0; r < 4; r++)
            xr[r] = bufA[(16*wq + 4*qd + r)*LS + 16*h + col];
        xreg[h] = xr;
    }
    __syncthreads();

    // rel-pos bias indices for S^T mapping: t = 16wq+col (fixed), u = 16jn+4qd+r
    int idx_t[4][4];
    {
        int t = 16*wq + col, ty = t >> 3, tx = t & 7;
        #pragma unroll
        for (int jn = 0; jn < 4; jn++)
            #pragma unroll
            for (int r = 0; r < 4; r++){
                int u = 16*jn + 4*qd + r;
                idx_t[jn][r] = (ty - (u>>3) + 7)*15 + (tx - (u&7) + 7);
            }
    }

    // ---- head loop: S^T -> thread-local softmax -> P (wave-private) -> PV -> Y/Y^T ----
    for (int h = 0; h < 4; h++){
        short8 bq = *(const short8*)&bufQ[(16*wq + col)*LS + h*16 + (qd & 1)*8];
        float pr[4][4];
        #pragma unroll
        for (int jn = 0; jn < 4; jn++){
            short8 ak = *(const short8*)&bufK[(16*jn + col)*LS + h*16 + (qd & 1)*8];
            if (qd >= 2) ak = zero8;
            float4v acc = MFMA(ak, bq, zf);
            #pragma unroll
            for (int r = 0; r < 4; r++)
                pr[jn][r] = acc[r] + rpb_lds[idx_t[jn][r]*4 + h];
        }
        // softmax over u: 16 values in-thread + qd lanes (xor16, xor32)
        float m = pr[0][0];
        #pragma unroll
        for (int jn = 0; jn < 4; jn++)
            #pragma unroll
            for (int r = 0; r < 4; r++) m = fmaxf(m, pr[jn][r]);
        m = fmaxf(m, __shfl_xor(m, 16));
        m = fmaxf(m, __shfl_xor(m, 32));
        float s = 0.f;
        #pragma unroll
        for (int jn = 0; jn < 4; jn++)
            #pragma unroll
            for (int r = 0; r < 4; r++){ pr[jn][r] = __expf(pr[jn][r] - m); s += pr[jn][r]; }
        s += __shfl_xor(s, 16);
        s += __shfl_xor(s, 32);
        float rc = 1.f / s;
        #pragma unroll
        for (int jn = 0; jn < 4; jn++){
            short4v pk;
            #pragma unroll
            for (int r = 0; r < 4; r++) pk[r] = f2bs(pr[jn][r] * rc);
            *(short4v*)&bufA[(16*wq + col)*LS + 16*jn + 4*qd] = pk;
        }
        // PV (P rows are wave-private: no barrier between write and read)
        short8 ap0 = *(const short8*)&bufA[(16*wq + col)*LS + 8*qd];
        short8 ap1 = *(const short8*)&bufA[(16*wq + col)*LS + 32 + 8*qd];
        short8 bv0 = *(const short8*)&bufV[(h*16 + col)*LS + 8*qd];
        short8 bv1 = *(const short8*)&bufV[(h*16 + col)*LS + 32 + 8*qd];
        float4v acc_o = zf;
        acc_o = MFMA(ap0, bv0, acc_o);
        acc_o = MFMA(ap1, bv1, acc_o);
        __syncthreads();          // all waves done reading V rows of this head
        short4v ot;
        #pragma unroll
        for (int r = 0; r < 4; r++) ot[r] = f2bs(acc_o[r]);
        *(short4v*)&bufV[(h*16 + col)*LS + 16*wq + 4*qd] = ot;   // Y^T
        #pragma unroll
        for (int r = 0; r < 4; r++)
            bufK[(16*wq + 4*qd + r)*LS + h*16 + col] = ot[r];    // Y
    }
    __syncthreads();

    // ---- energy = Y Y^T (16x16, K=256) ----
    {
        float4v acc_e = zf;
        #pragma unroll
        for (int h = 0; h < 4; h++){
            short8 f0 = *(const short8*)&bufV[(h*16 + col)*LS + 8*qd];
            short8 f1 = *(const short8*)&bufV[(h*16 + col)*LS + 32 + 8*qd];
            acc_e = MFMA(f0, f0, acc_e);
            acc_e = MFMA(f1, f1, acc_e);
        }
        if (wq == 0){
            #pragma unroll
            for (int r = 0; r < 4; r++) energyS[(4*qd + r)*16 + col] = acc_e[r];
        }
    }
    __syncthreads();
    if (tid < 16){
        int i = tid; float m = -1e30f;
        for (int j = 0; j < 16; j++) m = fmaxf(m, energyS[i*16 + j]);
        float s = 0.f; float e[16];
        for (int j = 0; j < 16; j++){ e[j] = __expf(energyS[i*16 + j] - m); s += e[j]; }
        float rc = 1.f / s;
        for (int j = 0; j < 16; j++) soft_bf[i*32 + j] = f2bs(e[j] * rc);
        for (int j = 0; j < 16; j++) soft_bf[i*32 + 16 + j] = 0;
    }
    __syncthreads();

    // ---- lam + assemble XO -> bufK (overwrite Y slots, wave-private rows) ----
    {
        float gam = gammap[0];
        short8 asf = *(const short8*)&soft_bf[col*32 + 8*qd];
        #pragma unroll
        for (int h = 0; h < 4; h++){
            short8 ay = *(const short8*)&bufK[(16*wq + col)*LS + 16*h + (qd & 1)*8];
            float4v acc = MFMA(ay, asf, zf);
            short4v xv = xreg[h];
            #pragma unroll
            for (int r = 0; r < 4; r++){
                int ro = (16*wq + 4*qd + r)*LS + 16*h + col;
                float ot = bs2f(bufK[ro]);
                float qv = bs2f(bufQ[ro]);
                float xo = gam*acc[r] + ot + qv + bs2f(xv[r]);
                bufK[ro] = f2bs(xo);
            }
        }
    }
    __syncthreads();

    // ---- proj: A = Wp rows c, B = XO rows t -> C[c][t]; write XOf[t*66+c] packed f2 ----
    {
        short8 a0 = load_w8(pw + (size_t)(16*wq + col)*64 + 8*qd);
        short8 a1 = load_w8(pw + (size_t)(16*wq + col)*64 + 32 + 8*qd);
        float pbr[4];
        #pragma unroll
        for (int r = 0; r < 4; r++) pbr[r] = pb[16*wq + 4*qd + r];
        #pragma unroll
        for (int jn = 0; jn < 4; jn++){
            int t = 16*jn + col;
            short8 bx0 = *(const short8*)&bufK[t*LS + 8*qd];
            short8 bx1 = *(const short8*)&bufK[t*LS + 32 + 8*qd];
            float4v acc = zf;
            acc = MFMA(a0, bx0, acc);
            acc = MFMA(a1, bx1, acc);
            float2v w0 = {acc[0]+pbr[0], acc[1]+pbr[1]};
            float2v w1 = {acc[2]+pbr[2], acc[3]+pbr[3]};
            *(float2v*)&XOf[t*66 + 16*wq + 4*qd]     = w0;
            *(float2v*)&XOf[t*66 + 16*wq + 4*qd + 2] = w1;
        }
    }
    __syncthreads();

    // ================= fused channel-MLP =================
    {
        int p = tid & 63, qg = tid >> 6;
        float s = 0.f, ss = 0.f;
        #pragma unroll
        for (int j = 0; j < 8; j++){
            float2v v = *(const float2v*)&XOf[p*66 + qg*16 + 2*j];
            s += v[0]+v[1]; ss += v[0]*v[0] + v[1]*v[1];
        }
        sumS[qg*64 + p] = s; sqS[qg*64 + p] = ss;
    }
    __syncthreads();
    if (tid < 64){
        float s  = sumS[tid] + sumS[64+tid] + sumS[128+tid] + sumS[192+tid];
        float ss = sqS[tid]  + sqS[64+tid]  + sqS[128+tid]  + sqS[192+tid];
        float m = s * (1.f/64.f);
        float var = ss * (1.f/64.f) - m*m;
        muS[tid] = m; rinvS[tid] = rsqrtf(var + EPS);
    }
    __syncthreads();
    // tn -> tnb (bf16, over bufA), packed b128 writes
    {
        int p = tid & 63, qg = tid >> 6;
        float m = muS[p], rv = rinvS[p];
        short8 o8[2];
        #pragma unroll
        for (int k = 0; k < 2; k++)
            #pragma unroll
            for (int j = 0; j < 8; j++){
                int c = qg*16 + k*8 + j;
                o8[k][j] = f2bs((XOf[p*66 + c] - m) * rv * n2g[c] + n2b[c]);
            }
        *(short8*)&tnb[p*LS + qg*16]     = o8[0];
        *(short8*)&tnb[p*LS + qg*16 + 8] = o8[1];
    }
    __syncthreads();
    // GEMM1: A = W1 rows j, B = tn rows t -> C[j][t]; h1b[t][j] packed
    {
        short8 a0 = load_w8(fw1 + (size_t)(16*wq + col)*64 + 8*qd);
        short8 a1 = load_w8(fw1 + (size_t)(16*wq + col)*64 + 32 + 8*qd);
        float fbr[4];
        #pragma unroll
        for (int r = 0; r < 4; r++) fbr[r] = fb1[16*wq + 4*qd + r];
        #pragma unroll
        for (int jn = 0; jn < 4; jn++){
            int t = 16*jn + col;
            short8 bx0 = *(const short8*)&tnb[t*LS + 8*qd];
            short8 bx1 = *(const short8*)&tnb[t*LS + 32 + 8*qd];
            float4v acc = zf;
            acc = MFMA(a0, bx0, acc);
            acc = MFMA(a1, bx1, acc);
            short4v pk;
            #pragma unroll
            for (int r = 0; r < 4; r++) pk[r] = f2bs(gelu_exact(acc[r] + fbr[r]));
            *(short4v*)&h1b[t*LS + 16*wq + 4*qd] = pk;
        }
    }
    __syncthreads();
    // GEMM2: out = xo + h1 @ W2^T + fb2 -> global (in place over x1)
    {
        short8 a0 = *(const short8*)&h1b[(16*wq + col)*LS + 8*qd];
        short8 a1 = *(const short8*)&h1b[(16*wq + col)*LS + 32 + 8*qd];
        #pragma unroll
        for (int jn = 0; jn < 4; jn++){
            int c2 = 16*jn + col;
            short8 f0 = load_w8(fw2 + (size_t)c2*64 + 8*qd);
            short8 f1 = load_w8(fw2 + (size_t)c2*64 + 32 + 8*qd);
            float4v acc = zf;
            acc = MFMA(a0, f0, acc);
            acc = MFMA(a1, f1, acc);
            float bv = fb2[c2];
            float4v ov;
            #pragma unroll
            for (int r = 0; r < 4; r++)
                ov[r] = acc[r] + bv + XOf[(16*wq + 4*qd + r)*66 + c2];
            int t0 = 16*wq + 4*qd;
            *(float4v*)(x1 + base + (size_t)c2*HW + HWOF(t0)) = ov;
        }
    }
    #undef HWOF
}

extern "C" void kernel_launch(void* const* d_in, const int* in_sizes, int n_in,
                              void* d_out, int out_size, void* d_ws, size_t ws_size,
                              hipStream_t stream){
    const float* x        = (const float*)d_in[0];
    const float* l1_g1    = (const float*)d_in[1];
    const float* l1_b1    = (const float*)d_in[2];
    const float* l1_cw    = (const float*)d_in[3];
    const float* l1_cb    = (const float*)d_in[4];
    const float* l1_g2    = (const float*)d_in[5];
    const float* l1_b2    = (const float*)d_in[6];
    const float* l2_g1    = (const float*)d_in[7];
    const float* l2_b1    = (const float*)d_in[8];
    const float* l2_cw    = (const float*)d_in[9];
    const float* l2_cb    = (const float*)d_in[10];
    const float* l2_g2    = (const float*)d_in[11];
    const float* l2_b2    = (const float*)d_in[12];
    const float* pos1     = (const float*)d_in[13];
    const float* pos2     = (const float*)d_in[14];
    const float* q_w      = (const float*)d_in[15];
    const float* q_b      = (const float*)d_in[16];
    const float* kv_w     = (const float*)d_in[17];
    const float* kv_b     = (const float*)d_in[18];
    const float* rpb      = (const float*)d_in[19];
    const float* gamma    = (const float*)d_in[20];
    const float* proj_w   = (const float*)d_in[21];
    const float* proj_b   = (const float*)d_in[22];
    const float* norm2_g  = (const float*)d_in[23];
    const float* norm2_b  = (const float*)d_in[24];
    const float* fc1_w    = (const float*)d_in[25];
    const float* fc1_b    = (const float*)d_in[26];
    const float* fc2_w    = (const float*)d_in[27];
    const float* fc2_b    = (const float*)d_in[28];

    float* out = (float*)d_out;                 // branch-1 conv out -> final, in place

    float* w2g   = (float*)d_ws;                // 16*NPLANE floats (67 MB), window-major branch-2
    float* partS = w2g + (size_t)16*NPLANE;     // 2048*256 floats (2 MB)
    float* partQ = partS + (size_t)2048*256;    // 2 MB
    float* mu1   = partQ + (size_t)2048*256;    // 1024
    float* rinv1 = mu1 + 1024;                  // 1024
    float* mu2   = rinv1 + 1024;                // 2048
    float* rinv2 = mu2 + 2048;                  // 2048

    k_stats<<<1024, 256, 0, stream>>>(x, mu1, rinv1);
    k_conv <<<4096, 256, 0, stream>>>(x, mu1, rinv1,
                                      l1_g1, l1_b1, l1_cw, l1_cb,
                                      l2_g1, l2_b1, l2_cw, l2_cb,
                                      out, w2g, partS, partQ);
    k_fin  <<<8, 256, 0, stream>>>(partS, partQ, mu2, rinv2);
    k_attn <<<4096, 256, 0, stream>>>(out, w2g, mu2, rinv2,
                                      l1_g2, l1_b2, l2_g2, l2_b2,
                                      pos1, pos2, q_w, q_b, kv_w, kv_b,
                                      rpb, gamma, proj_w, proj_b,
                                      norm2_g, norm2_b, fc1_w, fc1_b, fc2_w, fc2_b);
}

// Round 3
// 366.103 us; speedup vs baseline: 1.5481x; 1.1463x over previous
//
#include <hip/hip_runtime.h>
#include <hip/hip_bf16.h>

typedef __hip_bfloat16 bf16;
typedef __attribute__((ext_vector_type(8))) short short8;
typedef __attribute__((ext_vector_type(4))) short short4v;
typedef __attribute__((ext_vector_type(4))) float float4v;
typedef __attribute__((ext_vector_type(2))) float float2v;

__device__ __forceinline__ short f2bs(float f){
    union { bf16 h; short s; } u; u.h = __float2bfloat16(f); return u.s;
}
__device__ __forceinline__ float bs2f(short s){
    return __uint_as_float(((unsigned)(unsigned short)s) << 16);
}
__device__ __forceinline__ float gelu_exact(float x){
    return 0.5f * x * (1.0f + erff(x * 0.70710678118654752440f));
}
#define MFMA(a,b,c) __builtin_amdgcn_mfma_f32_16x16x32_bf16((a),(b),(c),0,0,0)

#define HW 16384
#define NPLANE 1048576
#define EPS 1e-5f
#define LS 72             // LDS row stride in bf16 (144 B)

// wb layout (shorts): 0:w1b 4096:w2b 8192:qwb 12288:kvwb(8192) 20480:pwb 24576:fw1b 28672:fw2b
#define OFF_W1   0
#define OFF_W2   4096
#define OFF_QW   8192
#define OFF_KVW  12288
#define OFF_PW   20480
#define OFF_FW1  24576
#define OFF_FW2  28672

// ---------------- Kernel 1: LN1 stats (blocks 0..1023) + weight prep (1024..1032) ----------------
__global__ __launch_bounds__(256) void k_pre(const float* __restrict__ x,
                                             float* __restrict__ mu,
                                             float* __restrict__ rinv,
                                             const float* __restrict__ w1, const float* __restrict__ w2,
                                             const float* __restrict__ qw, const float* __restrict__ kvw,
                                             const float* __restrict__ pw, const float* __restrict__ fw1,
                                             const float* __restrict__ fw2,
                                             short* __restrict__ wb, float* __restrict__ rowsum){
    int bi = blockIdx.x;
    int tid = threadIdx.x;
    if (bi < 1024){
        const float* p = x + (size_t)bi * HW;
        float s = 0.f, ss = 0.f;
        for (int i = tid; i < HW/4; i += 256){
            float4v v = *(const float4v*)(p + i*4);
            #pragma unroll
            for (int k = 0; k < 4; k++){ s += v[k]; ss += v[k]*v[k]; }
        }
        __shared__ float rs[256], rss[256];
        rs[tid] = s; rss[tid] = ss; __syncthreads();
        for (int st = 128; st > 0; st >>= 1){
            if (tid < st){ rs[tid] += rs[tid+st]; rss[tid] += rss[tid+st]; }
            __syncthreads();
        }
        if (tid == 0){
            float m = rs[0] * (1.f/HW);
            float v = rss[0] * (1.f/HW) - m*m;
            mu[bi] = m; rinv[bi] = rsqrtf(v + EPS);
        }
    } else if (bi < 1032){
        int wi = bi - 1024;
        const float* src = wi==0?w1: wi==1?w2: wi==2?qw: wi==3?kvw: wi==4?(kvw+4096): wi==5?pw: wi==6?fw1: fw2;
        short* dst = wb + wi*4096;
        int base = tid*16;
        short8 o8[2];
        #pragma unroll
        for (int k = 0; k < 2; k++){
            float4v v0 = *(const float4v*)(src + base + 8*k);
            float4v v1 = *(const float4v*)(src + base + 8*k + 4);
            #pragma unroll
            for (int j = 0; j < 4; j++){ o8[k][j] = f2bs(v0[j]); o8[k][4+j] = f2bs(v1[j]); }
        }
        *(short8*)&dst[base]     = o8[0];
        *(short8*)&dst[base + 8] = o8[1];
    } else {
        if (tid < 128){
            int br = tid >> 6, o = tid & 63;
            const float* W = br ? w2 : w1;
            float s = 0.f;
            for (int c = 0; c < 64; c++) s += W[o*64 + c];
            rowsum[br*64 + o] = s;
        }
    }
}

// ---------------- Kernel 2: LN1 + 1x1 conv, both branches (MFMA) ----------------
// br0 -> y1 planar fp32 (d_out); br1 -> w2g window-major fp32 ([b][win][t][c])
// LN2 partials -> partS/partQ [br][b][o][tile] (no atomics)
__global__ __launch_bounds__(256) void k_conv(const float* __restrict__ x,
                                              const float* __restrict__ mu,
                                              const float* __restrict__ rinv,
                                              const float* __restrict__ g1a, const float* __restrict__ b1a,
                                              const float* __restrict__ cb1,
                                              const float* __restrict__ g1b, const float* __restrict__ b1b,
                                              const float* __restrict__ cb2,
                                              const short* __restrict__ wb,
                                              const float* __restrict__ rowsum,
                                              float* __restrict__ y1, float* __restrict__ w2g,
                                              float* __restrict__ partS, float* __restrict__ partQ){
    int blk = blockIdx.x;          // 16*256 blocks
    int b = blk >> 8; int tile = blk & 255; int hw0 = tile * 64;
    __shared__ __align__(16) short xn_bf[64*LS];
    const int tid = threadIdx.x;
    const int wq = tid >> 6, lane = tid & 63, qd = lane >> 4, col = lane & 15;
    const float4v zf = {0.f,0.f,0.f,0.f};

    // stage LN1(x) -> xn_bf [p][c]; lane owns row p, 16 channels: b128 writes, conflict-free
    {
        int p = tid & 63, cq = tid >> 6;
        const float* xb = x + (size_t)(b*64 + 16*cq)*HW + hw0 + p;
        float4v m4[4], r4[4];
        #pragma unroll
        for (int k = 0; k < 4; k++){
            m4[k] = *(const float4v*)(mu   + b*64 + 16*cq + 4*k);
            r4[k] = *(const float4v*)(rinv + b*64 + 16*cq + 4*k);
        }
        short8 o8[2];
        #pragma unroll
        for (int k = 0; k < 2; k++)
            #pragma unroll
            for (int j = 0; j < 8; j++){
                int jj = 8*k + j;
                float v = xb[(size_t)jj*HW];
                o8[k][j] = f2bs((v - m4[jj>>2][jj&3]) * r4[jj>>2][jj&3]);
            }
        *(short8*)&xn_bf[p*LS + 16*cq]     = o8[0];
        *(short8*)&xn_bf[p*LS + 16*cq + 8] = o8[1];
    }
    __syncthreads();

    #pragma unroll
    for (int br = 0; br < 2; br++){
        const short* W  = wb + (br ? OFF_W2 : OFF_W1);
        const float* cb = br ? cb2 : cb1;
        const float* gp = br ? g1b : g1a;
        const float* bp = br ? b1b : b1a;
        short8 a0 = *(const short8*)&W[(16*wq + col)*64 + 8*qd];
        short8 a1 = *(const short8*)&W[(16*wq + col)*64 + 32 + 8*qd];
        float cbv[4], rsv[4];
        #pragma unroll
        for (int r = 0; r < 4; r++){
            int o = 16*wq + 4*qd + r;
            cbv[r] = cb[o]; rsv[r] = rowsum[br*64 + o];
        }
        float sa[4]  = {0.f,0.f,0.f,0.f};
        float ssa[4] = {0.f,0.f,0.f,0.f};
        #pragma unroll
        for (int jn = 0; jn < 4; jn++){
            short8 bx0 = *(const short8*)&xn_bf[(16*jn + col)*LS + 8*qd];
            short8 bx1 = *(const short8*)&xn_bf[(16*jn + col)*LS + 32 + 8*qd];
            float4v acc = zf;
            acc = MFMA(a0, bx0, acc);
            acc = MFMA(a1, bx1, acc);
            int hw = hw0 + 16*jn + col;
            float gl = gp[hw], bl = bp[hw];
            float vals[4];
            #pragma unroll
            for (int r = 0; r < 4; r++){
                vals[r] = gl*acc[r] + bl*rsv[r] + cbv[r];
                sa[r]  += vals[r];
                ssa[r] += vals[r]*vals[r];
            }
            if (br == 0){
                #pragma unroll
                for (int r = 0; r < 4; r++)
                    y1[(size_t)(b*64 + 16*wq + 4*qd + r)*HW + hw] = vals[r];
            } else {
                int row = hw >> 7, cc = hw & 127;
                int win = (row >> 3)*16 + (cc >> 3);
                int t   = (row & 7)*8 + (cc & 7);
                float4v vv;
                #pragma unroll
                for (int r = 0; r < 4; r++) vv[r] = vals[r];
                *(float4v*)(w2g + ((size_t)(b*256 + win)*64 + t)*64 + 16*wq + 4*qd) = vv;
            }
        }
        #pragma unroll
        for (int r = 0; r < 4; r++){
            float s = sa[r], ss = ssa[r];
            s += __shfl_xor(s, 1); ss += __shfl_xor(ss, 1);
            s += __shfl_xor(s, 2); ss += __shfl_xor(ss, 2);
            s += __shfl_xor(s, 4); ss += __shfl_xor(ss, 4);
            s += __shfl_xor(s, 8); ss += __shfl_xor(ss, 8);
            if (col == 0){
                int o = 16*wq + 4*qd + r;
                size_t pi = ((size_t)(br*16 + b)*64 + o)*256 + tile;
                partS[pi] = s; partQ[pi] = ss;
            }
        }
    }
}

// ---------------- Kernel 3: reduce LN2 partials (2048 rows x 256 tiles) ----------------
__global__ __launch_bounds__(256) void k_fin(const float* __restrict__ partS,
                                             const float* __restrict__ partQ,
                                             float* __restrict__ mu2,
                                             float* __restrict__ rinv2){
    int i = blockIdx.x*256 + threadIdx.x;    // br*1024 + b*64 + o
    const float* ps = partS + (size_t)i*256;
    const float* pq = partQ + (size_t)i*256;
    float s = 0.f, ss = 0.f;
    for (int k = 0; k < 64; k++){
        float4v a = *(const float4v*)(ps + k*4);
        float4v b = *(const float4v*)(pq + k*4);
        s += a[0]+a[1]+a[2]+a[3];
        ss += b[0]+b[1]+b[2]+b[3];
    }
    float m = s * (1.f/HW);
    float v = ss * (1.f/HW) - m*m;
    mu2[i] = m; rinv2[i] = rsqrtf(v + EPS);
}

// ---------------- Kernel 4: LN2+GELU on load + attention + LAM + proj + channel-MLP ----------------
__global__ __launch_bounds__(256, 4) void k_attn(float* __restrict__ x1, const float* __restrict__ w2g,
                                              const float* __restrict__ mu2, const float* __restrict__ rinv2,
                                              const float* __restrict__ g2a, const float* __restrict__ b2a,
                                              const float* __restrict__ g2b, const float* __restrict__ b2b,
                                              const float* __restrict__ pos1, const float* __restrict__ pos2,
                                              const short* __restrict__ wb,
                                              const float* __restrict__ qb, const float* __restrict__ kvb,
                                              const float* __restrict__ rpb, const float* __restrict__ gammap,
                                              const float* __restrict__ pb,
                                              const float* __restrict__ n2g, const float* __restrict__ n2b,
                                              const float* __restrict__ fb1,
                                              const float* __restrict__ fb2){
    int B = blockIdx.x;
    int hy = (B & 7) | ((B >> 5) & 8);
    int wx = (((B >> 9) & 7) << 1) | ((B >> 3) & 1);
    int b  = (B >> 4) & 15;
    int win = hy*16 + wx;

    const short* qwb  = wb + OFF_QW;
    const short* kvwb = wb + OFF_KVW;
    const short* pwb  = wb + OFF_PW;
    const short* f1b  = wb + OFF_FW1;
    const short* f2b  = wb + OFF_FW2;

    __shared__ __align__(16) char smem[40464];
    short* bufA = (short*)smem;                    // X2w -> X1w -> P (wave-private)
    short* bufK = (short*)(smem + 9216);           // K -> Y[t][c] -> XO[t][c]
    short* bufV = (short*)(smem + 18432);          // V^T[c][t] -> Y^T[c][t]
    short* bufQ = (short*)(smem + 27648);          // Q[t][c]
    float* rpb_lds = (float*)(smem + 36864);       // 3600 (dead after head loop)
    float* energyS = (float*)(smem + 36864);       // 1024, aliases rpb
    short* soft_bf = (short*)(smem + 37888);       // 1024, aliases rpb
    // tail aliases:
    float* XOf  = (float*)(smem + 18432);          // 64x66 fp32 (16896 B) over bufV+bufQ
    short* tnb  = (short*)smem;                    // tn bf16 over bufA
    short* h1b  = (short*)(smem + 9216);           // h1 over bufK
    float* sumS = (float*)(smem + 36864);          // 1024
    float* sqS  = (float*)(smem + 37888);          // 1024
    float* muS  = (float*)(smem + 38912);          // 256
    float* rinvS= (float*)(smem + 39168);          // 256

    const int tid = threadIdx.x;
    const int wq = tid >> 6, lane = tid & 63, qd = lane >> 4, col = lane & 15;
    size_t base = (size_t)b * NPLANE;
    #define HWOF(t) ((hy*8 + ((t)>>3))*128 + wx*8 + ((t)&7))

    const float4v zf = {0.f,0.f,0.f,0.f};
    const short8 zero8 = {0,0,0,0,0,0,0,0};

    for (int i = tid; i < 900; i += 256) rpb_lds[i] = rpb[i];

    // ---- load X2 window (contiguous w2g) + LN2b + GELU + pos2 -> bufA [t][c] ----
    {
        const float* src = w2g + ((size_t)(b*256 + win) << 12);
        int t = tid >> 2, c0 = (tid & 3) << 4;
        int hw = HWOF(t);
        float g = g2b[hw], lb = b2b[hw];
        const float* mup = mu2   + 1024 + b*64 + c0;
        const float* rvp = rinv2 + 1024 + b*64 + c0;
        short8 o8[2];
        #pragma unroll
        for (int k = 0; k < 4; k++){
            float4v v  = *(const float4v*)(src + (size_t)t*64 + c0 + 4*k);
            float4v m4 = *(const float4v*)(mup + 4*k);
            float4v r4 = *(const float4v*)(rvp + 4*k);
            float4v p4 = *(const float4v*)(pos2 + t*64 + c0 + 4*k);
            #pragma unroll
            for (int j = 0; j < 4; j++){
                float z = (v[j] - m4[j]) * r4[j] * g + lb;
                o8[k>>1][(k&1)*4 + j] = f2bs(gelu_exact(z) + p4[j]);
            }
        }
        *(short8*)&bufA[t*LS + c0]     = o8[0];
        *(short8*)&bufA[t*LS + c0 + 8] = o8[1];
    }
    __syncthreads();

    // ---- V^T and K, both with packed b64 write-backs ----
    {
        short8 ax0 = *(const short8*)&bufA[(16*wq + col)*LS + 8*qd];
        short8 ax1 = *(const short8*)&bufA[(16*wq + col)*LS + 32 + 8*qd];
        // V^T: C[t][c] -> write bufV[c][t] packed
        #pragma unroll
        for (int jn = 0; jn < 4; jn++){
            int c = 16*jn + col;
            short8 wv0 = *(const short8*)&kvwb[(64 + c)*64 + 8*qd];
            short8 wv1 = *(const short8*)&kvwb[(64 + c)*64 + 32 + 8*qd];
            float4v acc = zf;
            acc = MFMA(ax0, wv0, acc);
            acc = MFMA(ax1, wv1, acc);
            float bv = kvb[64 + c];
            short4v pk;
            #pragma unroll
            for (int r = 0; r < 4; r++) pk[r] = f2bs(acc[r] + bv);
            *(short4v*)&bufV[c*LS + 16*wq + 4*qd] = pk;
        }
        // K: write bufK[t][c] packed
        short8 a0 = *(const short8*)&kvwb[(16*wq + col)*64 + 8*qd];
        short8 a1 = *(const short8*)&kvwb[(16*wq + col)*64 + 32 + 8*qd];
        float kbr[4];
        #pragma unroll
        for (int r = 0; r < 4; r++) kbr[r] = kvb[16*wq + 4*qd + r];
        #pragma unroll
        for (int jn = 0; jn < 4; jn++){
            int t = 16*jn + col;
            short8 bx0 = *(const short8*)&bufA[t*LS + 8*qd];
            short8 bx1 = *(const short8*)&bufA[t*LS + 32 + 8*qd];
            float4v acc = zf;
            acc = MFMA(a0, bx0, acc);
            acc = MFMA(a1, bx1, acc);
            short4v pk;
            #pragma unroll
            for (int r = 0; r < 4; r++) pk[r] = f2bs(acc[r] + kbr[r]);
            *(short4v*)&bufK[t*LS + 16*wq + 4*qd] = pk;
        }
    }
    __syncthreads();

    // ---- load X1 (planar) + LN2a + GELU + pos1 -> bufA [t][c]; lane owns row t ----
    {
        int t = tid & 63, cq = tid >> 6;     // c = 16cq + 8k + j
        int hw = HWOF(t);
        float g = g2a[hw], lb = b2a[hw];
        const float* mup = mu2   + b*64 + 16*cq;
        const float* rvp = rinv2 + b*64 + 16*cq;
        float4v m4[4], r4[4], p4[4];
        #pragma unroll
        for (int k = 0; k < 4; k++){
            m4[k] = *(const float4v*)(mup + 4*k);
            r4[k] = *(const float4v*)(rvp + 4*k);
            p4[k] = *(const float4v*)(pos1 + t*64 + 16*cq + 4*k);
        }
        short8 o8[2];
        #pragma unroll
        for (int k = 0; k < 2; k++)
            #pragma unroll
            for (int j = 0; j < 8; j++){
                int jj = 8*k + j;
                float v = x1[base + (size_t)(16*cq + jj)*HW + hw];
                float z = (v - m4[jj>>2][jj&3]) * r4[jj>>2][jj&3] * g + lb;
                o8[k][j] = f2bs(gelu_exact(z) + p4[jj>>2][jj&3]);
            }
        *(short8*)&bufA[t*LS + 16*cq]     = o8[0];
        *(short8*)&bufA[t*LS + 16*cq + 8] = o8[1];
    }
    __syncthreads();

    // ---- Q: C[c][t] -> write bufQ[t][c] packed ----
    {
        short8 a0 = *(const short8*)&qwb[(16*wq + col)*64 + 8*qd];
        short8 a1 = *(const short8*)&qwb[(16*wq + col)*64 + 32 + 8*qd];
        float qbr[4];
        #pragma unroll
        for (int r = 0; r < 4; r++) qbr[r] = qb[16*wq + 4*qd + r];
        #pragma unroll
        for (int jn = 0; jn < 4; jn++){
            int t = 16*jn + col;
            short8 bx0 = *(const short8*)&bufA[t*LS + 8*qd];
            short8 bx1 = *(const short8*)&bufA[t*LS + 32 + 8*qd];
            float4v acc = zf;
            acc = MFMA(a0, bx0, acc);
            acc = MFMA(a1, bx1, acc);
            short4v pk;
            #pragma unroll
            for (int r = 0; r < 4; r++) pk[r] = f2bs((acc[r] + qbr[r]) * 0.25f);
            *(short4v*)&bufQ[t*LS + 16*wq + 4*qd] = pk;
        }
    }
    // capture X1w values needed at XO-assembly (own-wave rows), then bufA becomes P
    short4v xreg[4];
    #pragma unroll
    for (int h = 0; h < 4; h++){
        short4v xr;
        #pragma unroll
        for (int r = 0; r < 4; r++)
            xr[r] = bufA[(16*wq + 4*qd + r)*LS + 16*h + col];
        xreg[h] = xr;
    }
    __syncthreads();

    // rel-pos bias indices for S^T mapping: t = 16wq+col (fixed), u = 16jn+4qd+r
    int idx_t[4][4];
    {
        int t = 16*wq + col, ty = t >> 3, tx = t & 7;
        #pragma unroll
        for (int jn = 0; jn < 4; jn++)
            #pragma unroll
            for (int r = 0; r < 4; r++){
                int u = 16*jn + 4*qd + r;
                idx_t[jn][r] = (ty - (u>>3) + 7)*15 + (tx - (u&7) + 7);
            }
    }

    // ---- head loop: S^T -> thread-local softmax -> P (wave-private) -> PV -> Y/Y^T ----
    for (int h = 0; h < 4; h++){
        short8 bq = *(const short8*)&bufQ[(16*wq + col)*LS + h*16 + (qd & 1)*8];
        float pr[4][4];
        #pragma unroll
        for (int jn = 0; jn < 4; jn++){
            short8 ak = *(const short8*)&bufK[(16*jn + col)*LS + h*16 + (qd & 1)*8];
            if (qd >= 2) ak = zero8;
            float4v acc = MFMA(ak, bq, zf);
            #pragma unroll
            for (int r = 0; r < 4; r++)
                pr[jn][r] = acc[r] + rpb_lds[idx_t[jn][r]*4 + h];
        }
        float m = pr[0][0];
        #pragma unroll
        for (int jn = 0; jn < 4; jn++)
            #pragma unroll
            for (int r = 0; r < 4; r++) m = fmaxf(m, pr[jn][r]);
        m = fmaxf(m, __shfl_xor(m, 16));
        m = fmaxf(m, __shfl_xor(m, 32));
        float s = 0.f;
        #pragma unroll
        for (int jn = 0; jn < 4; jn++)
            #pragma unroll
            for (int r = 0; r < 4; r++){ pr[jn][r] = __expf(pr[jn][r] - m); s += pr[jn][r]; }
        s += __shfl_xor(s, 16);
        s += __shfl_xor(s, 32);
        float rc = 1.f / s;
        #pragma unroll
        for (int jn = 0; jn < 4; jn++){
            short4v pk;
            #pragma unroll
            for (int r = 0; r < 4; r++) pk[r] = f2bs(pr[jn][r] * rc);
            *(short4v*)&bufA[(16*wq + col)*LS + 16*jn + 4*qd] = pk;
        }
        short8 ap0 = *(const short8*)&bufA[(16*wq + col)*LS + 8*qd];
        short8 ap1 = *(const short8*)&bufA[(16*wq + col)*LS + 32 + 8*qd];
        short8 bv0 = *(const short8*)&bufV[(h*16 + col)*LS + 8*qd];
        short8 bv1 = *(const short8*)&bufV[(h*16 + col)*LS + 32 + 8*qd];
        float4v acc_o = zf;
        acc_o = MFMA(ap0, bv0, acc_o);
        acc_o = MFMA(ap1, bv1, acc_o);
        __syncthreads();          // all waves done reading V rows of this head
        short4v ot;
        #pragma unroll
        for (int r = 0; r < 4; r++) ot[r] = f2bs(acc_o[r]);
        *(short4v*)&bufV[(h*16 + col)*LS + 16*wq + 4*qd] = ot;   // Y^T
        #pragma unroll
        for (int r = 0; r < 4; r++)
            bufK[(16*wq + 4*qd + r)*LS + h*16 + col] = ot[r];    // Y
    }
    __syncthreads();

    // ---- energy = Y Y^T (16x16, K=256) ----
    {
        float4v acc_e = zf;
        #pragma unroll
        for (int h = 0; h < 4; h++){
            short8 f0 = *(const short8*)&bufV[(h*16 + col)*LS + 8*qd];
            short8 f1 = *(const short8*)&bufV[(h*16 + col)*LS + 32 + 8*qd];
            acc_e = MFMA(f0, f0, acc_e);
            acc_e = MFMA(f1, f1, acc_e);
        }
        if (wq == 0){
            #pragma unroll
            for (int r = 0; r < 4; r++) energyS[(4*qd + r)*16 + col] = acc_e[r];
        }
    }
    __syncthreads();
    if (tid < 16){
        int i = tid; float m = -1e30f;
        for (int j = 0; j < 16; j++) m = fmaxf(m, energyS[i*16 + j]);
        float s = 0.f; float e[16];
        for (int j = 0; j < 16; j++){ e[j] = __expf(energyS[i*16 + j] - m); s += e[j]; }
        float rc = 1.f / s;
        for (int j = 0; j < 16; j++) soft_bf[i*32 + j] = f2bs(e[j] * rc);
        for (int j = 0; j < 16; j++) soft_bf[i*32 + 16 + j] = 0;
    }
    __syncthreads();

    // ---- lam + assemble XO -> bufK (overwrite Y slots, wave-private rows) ----
    {
        float gam = gammap[0];
        short8 asf = *(const short8*)&soft_bf[col*32 + 8*qd];
        #pragma unroll
        for (int h = 0; h < 4; h++){
            short8 ay = *(const short8*)&bufK[(16*wq + col)*LS + 16*h + (qd & 1)*8];
            float4v acc = MFMA(ay, asf, zf);
            short4v xv = xreg[h];
            #pragma unroll
            for (int r = 0; r < 4; r++){
                int ro = (16*wq + 4*qd + r)*LS + 16*h + col;
                float ot = bs2f(bufK[ro]);
                float qv = bs2f(bufQ[ro]);
                float xo = gam*acc[r] + ot + qv + bs2f(xv[r]);
                bufK[ro] = f2bs(xo);
            }
        }
    }
    __syncthreads();

    // ---- proj: C[c][t] -> XOf[t*66+c] packed f2 ----
    {
        short8 a0 = *(const short8*)&pwb[(16*wq + col)*64 + 8*qd];
        short8 a1 = *(const short8*)&pwb[(16*wq + col)*64 + 32 + 8*qd];
        float pbr[4];
        #pragma unroll
        for (int r = 0; r < 4; r++) pbr[r] = pb[16*wq + 4*qd + r];
        #pragma unroll
        for (int jn = 0; jn < 4; jn++){
            int t = 16*jn + col;
            short8 bx0 = *(const short8*)&bufK[t*LS + 8*qd];
            short8 bx1 = *(const short8*)&bufK[t*LS + 32 + 8*qd];
            float4v acc = zf;
            acc = MFMA(a0, bx0, acc);
            acc = MFMA(a1, bx1, acc);
            float2v w0 = {acc[0]+pbr[0], acc[1]+pbr[1]};
            float2v w1 = {acc[2]+pbr[2], acc[3]+pbr[3]};
            *(float2v*)&XOf[t*66 + 16*wq + 4*qd]     = w0;
            *(float2v*)&XOf[t*66 + 16*wq + 4*qd + 2] = w1;
        }
    }
    __syncthreads();

    // ================= fused channel-MLP =================
    {
        int p = tid & 63, qg = tid >> 6;
        float s = 0.f, ss = 0.f;
        #pragma unroll
        for (int j = 0; j < 8; j++){
            float2v v = *(const float2v*)&XOf[p*66 + qg*16 + 2*j];
            s += v[0]+v[1]; ss += v[0]*v[0] + v[1]*v[1];
        }
        sumS[qg*64 + p] = s; sqS[qg*64 + p] = ss;
    }
    __syncthreads();
    if (tid < 64){
        float s  = sumS[tid] + sumS[64+tid] + sumS[128+tid] + sumS[192+tid];
        float ss = sqS[tid]  + sqS[64+tid]  + sqS[128+tid]  + sqS[192+tid];
        float m = s * (1.f/64.f);
        float var = ss * (1.f/64.f) - m*m;
        muS[tid] = m; rinvS[tid] = rsqrtf(var + EPS);
    }
    __syncthreads();
    // tn -> tnb (bf16, over bufA), packed b128 writes
    {
        int p = tid & 63, qg = tid >> 6;
        float m = muS[p], rv = rinvS[p];
        short8 o8[2];
        #pragma unroll
        for (int k = 0; k < 2; k++)
            #pragma unroll
            for (int j = 0; j < 8; j++){
                int c = qg*16 + k*8 + j;
                o8[k][j] = f2bs((XOf[p*66 + c] - m) * rv * n2g[c] + n2b[c]);
            }
        *(short8*)&tnb[p*LS + qg*16]     = o8[0];
        *(short8*)&tnb[p*LS + qg*16 + 8] = o8[1];
    }
    __syncthreads();
    // GEMM1: C[j][t]; h1b[t][j] packed
    {
        short8 a0 = *(const short8*)&f1b[(16*wq + col)*64 + 8*qd];
        short8 a1 = *(const short8*)&f1b[(16*wq + col)*64 + 32 + 8*qd];
        float fbr[4];
        #pragma unroll
        for (int r = 0; r < 4; r++) fbr[r] = fb1[16*wq + 4*qd + r];
        #pragma unroll
        for (int jn = 0; jn < 4; jn++){
            int t = 16*jn + col;
            short8 bx0 = *(const short8*)&tnb[t*LS + 8*qd];
            short8 bx1 = *(const short8*)&tnb[t*LS + 32 + 8*qd];
            float4v acc = zf;
            acc = MFMA(a0, bx0, acc);
            acc = MFMA(a1, bx1, acc);
            short4v pk;
            #pragma unroll
            for (int r = 0; r < 4; r++) pk[r] = f2bs(gelu_exact(acc[r] + fbr[r]));
            *(short4v*)&h1b[t*LS + 16*wq + 4*qd] = pk;
        }
    }
    __syncthreads();
    // GEMM2: out = xo + h1 @ W2^T + fb2 -> global (in place over x1)
    {
        short8 a0 = *(const short8*)&h1b[(16*wq + col)*LS + 8*qd];
        short8 a1 = *(const short8*)&h1b[(16*wq + col)*LS + 32 + 8*qd];
        #pragma unroll
        for (int jn = 0; jn < 4; jn++){
            int c2 = 16*jn + col;
            short8 f0 = *(const short8*)&f2b[c2*64 + 8*qd];
            short8 f1 = *(const short8*)&f2b[c2*64 + 32 + 8*qd];
            float4v acc = zf;
            acc = MFMA(a0, f0, acc);
            acc = MFMA(a1, f1, acc);
            float bv = fb2[c2];
            float4v ov;
            #pragma unroll
            for (int r = 0; r < 4; r++)
                ov[r] = acc[r] + bv + XOf[(16*wq + 4*qd + r)*66 + c2];
            int t0 = 16*wq + 4*qd;
            *(float4v*)(x1 + base + (size_t)c2*HW + HWOF(t0)) = ov;
        }
    }
    #undef HWOF
}

extern "C" void kernel_launch(void* const* d_in, const int* in_sizes, int n_in,
                              void* d_out, int out_size, void* d_ws, size_t ws_size,
                              hipStream_t stream){
    const float* x        = (const float*)d_in[0];
    const float* l1_g1    = (const float*)d_in[1];
    const float* l1_b1    = (const float*)d_in[2];
    const float* l1_cw    = (const float*)d_in[3];
    const float* l1_cb    = (const float*)d_in[4];
    const float* l1_g2    = (const float*)d_in[5];
    const float* l1_b2    = (const float*)d_in[6];
    const float* l2_g1    = (const float*)d_in[7];
    const float* l2_b1    = (const float*)d_in[8];
    const float* l2_cw    = (const float*)d_in[9];
    const float* l2_cb    = (const float*)d_in[10];
    const float* l2_g2    = (const float*)d_in[11];
    const float* l2_b2    = (const float*)d_in[12];
    const float* pos1     = (const float*)d_in[13];
    const float* pos2     = (const float*)d_in[14];
    const float* q_w      = (const float*)d_in[15];
    const float* q_b      = (const float*)d_in[16];
    const float* kv_w     = (const float*)d_in[17];
    const float* kv_b     = (const float*)d_in[18];
    const float* rpb      = (const float*)d_in[19];
    const float* gamma    = (const float*)d_in[20];
    const float* proj_w   = (const float*)d_in[21];
    const float* proj_b   = (const float*)d_in[22];
    const float* norm2_g  = (const float*)d_in[23];
    const float* norm2_b  = (const float*)d_in[24];
    const float* fc1_w    = (const float*)d_in[25];
    const float* fc1_b    = (const float*)d_in[26];
    const float* fc2_w    = (const float*)d_in[27];
    const float* fc2_b    = (const float*)d_in[28];

    float* out = (float*)d_out;                 // branch-1 conv out -> final, in place

    float* w2g   = (float*)d_ws;                // 16*NPLANE floats (67 MB), window-major branch-2
    float* partS = w2g + (size_t)16*NPLANE;     // 2 MB
    float* partQ = partS + (size_t)2048*256;    // 2 MB
    float* mu1   = partQ + (size_t)2048*256;    // 1024
    float* rinv1 = mu1 + 1024;                  // 1024
    float* mu2   = rinv1 + 1024;                // 2048
    float* rinv2 = mu2 + 2048;                  // 2048
    float* rowsumG = rinv2 + 2048;              // 128
    short* wbuf  = (short*)(rowsumG + 128);     // 32768 shorts

    k_pre  <<<1033, 256, 0, stream>>>(x, mu1, rinv1,
                                      l1_cw, l2_cw, q_w, kv_w, proj_w, fc1_w, fc2_w,
                                      wbuf, rowsumG);
    k_conv <<<4096, 256, 0, stream>>>(x, mu1, rinv1,
                                      l1_g1, l1_b1, l1_cb,
                                      l2_g1, l2_b1, l2_cb,
                                      wbuf, rowsumG,
                                      out, w2g, partS, partQ);
    k_fin  <<<8, 256, 0, stream>>>(partS, partQ, mu2, rinv2);
    k_attn <<<4096, 256, 0, stream>>>(out, w2g, mu2, rinv2,
                                      l1_g2, l1_b2, l2_g2, l2_b2,
                                      pos1, pos2, wbuf, q_b, kv_b,
                                      rpb, gamma, proj_b,
                                      norm2_g, norm2_b, fc1_b, fc2_b);
}

// Round 4
// 322.929 us; speedup vs baseline: 1.7551x; 1.1337x over previous
//
#include <hip/hip_runtime.h>
#include <hip/hip_bf16.h>

typedef __hip_bfloat16 bf16;
typedef __attribute__((ext_vector_type(8))) short short8;
typedef __attribute__((ext_vector_type(4))) short short4v;
typedef __attribute__((ext_vector_type(4))) float float4v;
typedef __attribute__((ext_vector_type(2))) float float2v;

__device__ __forceinline__ short f2bs(float f){
    union { bf16 h; short s; } u; u.h = __float2bfloat16(f); return u.s;
}
__device__ __forceinline__ float bs2f(short s){
    return __uint_as_float(((unsigned)(unsigned short)s) << 16);
}
__device__ __forceinline__ float gelu_exact(float x){
    return 0.5f * x * (1.0f + erff(x * 0.70710678118654752440f));
}
#define MFMA(a,b,c) __builtin_amdgcn_mfma_f32_16x16x32_bf16((a),(b),(c),0,0,0)

#define HW 16384
#define NPLANE 1048576
#define EPS 1e-5f
#define LS 72             // LDS row stride in bf16 (144 B)

// wb layout (shorts): 0:w1b 4096:w2b 8192:qwb 12288:kvwb(8192) 20480:pwb 24576:fw1b 28672:fw2b
#define OFF_W1   0
#define OFF_W2   4096
#define OFF_QW   8192
#define OFF_KVW  12288
#define OFF_PW   20480
#define OFF_FW1  24576
#define OFF_FW2  28672

// ---------------- Kernel 1: LN1 stats (blocks 0..1023) + weight prep (1024..1032) ----------------
__global__ __launch_bounds__(256) void k_pre(const float* __restrict__ x,
                                             float* __restrict__ mu,
                                             float* __restrict__ rinv,
                                             const float* __restrict__ w1, const float* __restrict__ w2,
                                             const float* __restrict__ qw, const float* __restrict__ kvw,
                                             const float* __restrict__ pw, const float* __restrict__ fw1,
                                             const float* __restrict__ fw2,
                                             short* __restrict__ wb, float* __restrict__ rowsum){
    int bi = blockIdx.x;
    int tid = threadIdx.x;
    if (bi < 1024){
        const float* p = x + (size_t)bi * HW;
        float s = 0.f, ss = 0.f;
        for (int i = tid; i < HW/4; i += 256){
            float4v v = *(const float4v*)(p + i*4);
            #pragma unroll
            for (int k = 0; k < 4; k++){ s += v[k]; ss += v[k]*v[k]; }
        }
        __shared__ float rs[256], rss[256];
        rs[tid] = s; rss[tid] = ss; __syncthreads();
        for (int st = 128; st > 0; st >>= 1){
            if (tid < st){ rs[tid] += rs[tid+st]; rss[tid] += rss[tid+st]; }
            __syncthreads();
        }
        if (tid == 0){
            float m = rs[0] * (1.f/HW);
            float v = rss[0] * (1.f/HW) - m*m;
            mu[bi] = m; rinv[bi] = rsqrtf(v + EPS);
        }
    } else if (bi < 1032){
        int wi = bi - 1024;
        const float* src = wi==0?w1: wi==1?w2: wi==2?qw: wi==3?kvw: wi==4?(kvw+4096): wi==5?pw: wi==6?fw1: fw2;
        short* dst = wb + wi*4096;
        int base = tid*16;
        short8 o8[2];
        #pragma unroll
        for (int k = 0; k < 2; k++){
            float4v v0 = *(const float4v*)(src + base + 8*k);
            float4v v1 = *(const float4v*)(src + base + 8*k + 4);
            #pragma unroll
            for (int j = 0; j < 4; j++){ o8[k][j] = f2bs(v0[j]); o8[k][4+j] = f2bs(v1[j]); }
        }
        *(short8*)&dst[base]     = o8[0];
        *(short8*)&dst[base + 8] = o8[1];
    } else {
        if (tid < 128){
            int br = tid >> 6, o = tid & 63;
            const float* W = br ? w2 : w1;
            float s = 0.f;
            for (int c = 0; c < 64; c++) s += W[o*64 + c];
            rowsum[br*64 + o] = s;
        }
    }
}

// ---------------- Kernel 2: LN1 + 1x1 conv, STATS ONLY (no conv-output stores) ----------------
// LN2 partials -> partS/partQ [br][b][o][tile]
__global__ __launch_bounds__(256) void k_conv(const float* __restrict__ x,
                                              const float* __restrict__ mu,
                                              const float* __restrict__ rinv,
                                              const float* __restrict__ g1a, const float* __restrict__ b1a,
                                              const float* __restrict__ cb1,
                                              const float* __restrict__ g1b, const float* __restrict__ b1b,
                                              const float* __restrict__ cb2,
                                              const short* __restrict__ wb,
                                              const float* __restrict__ rowsum,
                                              float* __restrict__ partS, float* __restrict__ partQ){
    int blk = blockIdx.x;          // 16*256 blocks
    int b = blk >> 8; int tile = blk & 255; int hw0 = tile * 64;
    __shared__ __align__(16) short xn_bf[64*LS];
    const int tid = threadIdx.x;
    const int wq = tid >> 6, lane = tid & 63, qd = lane >> 4, col = lane & 15;
    const float4v zf = {0.f,0.f,0.f,0.f};

    // stage LN1(x) -> xn_bf [p][c]; lane owns row p, 16 channels: b128 writes
    {
        int p = tid & 63, cq = tid >> 6;
        const float* xb = x + (size_t)(b*64 + 16*cq)*HW + hw0 + p;
        float4v m4[4], r4[4];
        #pragma unroll
        for (int k = 0; k < 4; k++){
            m4[k] = *(const float4v*)(mu   + b*64 + 16*cq + 4*k);
            r4[k] = *(const float4v*)(rinv + b*64 + 16*cq + 4*k);
        }
        short8 o8[2];
        #pragma unroll
        for (int k = 0; k < 2; k++)
            #pragma unroll
            for (int j = 0; j < 8; j++){
                int jj = 8*k + j;
                float v = xb[(size_t)jj*HW];
                o8[k][j] = f2bs((v - m4[jj>>2][jj&3]) * r4[jj>>2][jj&3]);
            }
        *(short8*)&xn_bf[p*LS + 16*cq]     = o8[0];
        *(short8*)&xn_bf[p*LS + 16*cq + 8] = o8[1];
    }
    __syncthreads();

    #pragma unroll
    for (int br = 0; br < 2; br++){
        const short* W  = wb + (br ? OFF_W2 : OFF_W1);
        const float* cb = br ? cb2 : cb1;
        const float* gp = br ? g1b : g1a;
        const float* bp = br ? b1b : b1a;
        short8 a0 = *(const short8*)&W[(16*wq + col)*64 + 8*qd];
        short8 a1 = *(const short8*)&W[(16*wq + col)*64 + 32 + 8*qd];
        float cbv[4], rsv[4];
        #pragma unroll
        for (int r = 0; r < 4; r++){
            int o = 16*wq + 4*qd + r;
            cbv[r] = cb[o]; rsv[r] = rowsum[br*64 + o];
        }
        float sa[4]  = {0.f,0.f,0.f,0.f};
        float ssa[4] = {0.f,0.f,0.f,0.f};
        #pragma unroll
        for (int jn = 0; jn < 4; jn++){
            short8 bx0 = *(const short8*)&xn_bf[(16*jn + col)*LS + 8*qd];
            short8 bx1 = *(const short8*)&xn_bf[(16*jn + col)*LS + 32 + 8*qd];
            float4v acc = zf;
            acc = MFMA(a0, bx0, acc);
            acc = MFMA(a1, bx1, acc);
            int hw = hw0 + 16*jn + col;
            float gl = gp[hw], bl = bp[hw];
            #pragma unroll
            for (int r = 0; r < 4; r++){
                float v = gl*acc[r] + bl*rsv[r] + cbv[r];
                sa[r]  += v;
                ssa[r] += v*v;
            }
        }
        #pragma unroll
        for (int r = 0; r < 4; r++){
            float s = sa[r], ss = ssa[r];
            s += __shfl_xor(s, 1); ss += __shfl_xor(ss, 1);
            s += __shfl_xor(s, 2); ss += __shfl_xor(ss, 2);
            s += __shfl_xor(s, 4); ss += __shfl_xor(ss, 4);
            s += __shfl_xor(s, 8); ss += __shfl_xor(ss, 8);
            if (col == 0){
                int o = 16*wq + 4*qd + r;
                size_t pi = ((size_t)(br*16 + b)*64 + o)*256 + tile;
                partS[pi] = s; partQ[pi] = ss;
            }
        }
    }
}

// ---------------- Kernel 3: reduce LN2 partials, wave-per-row ----------------
__global__ __launch_bounds__(256) void k_fin(const float* __restrict__ partS,
                                             const float* __restrict__ partQ,
                                             float* __restrict__ mu2,
                                             float* __restrict__ rinv2){
    int row = blockIdx.x*4 + (threadIdx.x >> 6);   // 0..2047
    int lane = threadIdx.x & 63;
    float4v a = *(const float4v*)(partS + (size_t)row*256 + lane*4);
    float4v b = *(const float4v*)(partQ + (size_t)row*256 + lane*4);
    float s  = a[0]+a[1]+a[2]+a[3];
    float ss = b[0]+b[1]+b[2]+b[3];
    #pragma unroll
    for (int st = 1; st < 64; st <<= 1){
        s  += __shfl_xor(s,  st);
        ss += __shfl_xor(ss, st);
    }
    if (lane == 0){
        float m = s * (1.f/HW);
        float v = ss * (1.f/HW) - m*m;
        mu2[row] = m; rinv2[row] = rsqrtf(v + EPS);
    }
}

// ---------------- Kernel 4: full fused window pipeline ----------------
// Loads raw x window, recomputes LN1+conv (both branches, bit-identical to k_conv's),
// applies LN2+GELU+pos in the conv epilogue, then attention + LAM + proj + MLP.
// Output written planar fp32 to outp (d_out), written exactly once.
__global__ __launch_bounds__(256, 4) void k_attn(const float* __restrict__ x, float* __restrict__ outp,
                                              const float* __restrict__ mu1, const float* __restrict__ rinv1,
                                              const float* __restrict__ rowsum,
                                              const float* __restrict__ cb1, const float* __restrict__ cb2,
                                              const float* __restrict__ g1a, const float* __restrict__ b1a,
                                              const float* __restrict__ g1b, const float* __restrict__ b1b,
                                              const float* __restrict__ mu2, const float* __restrict__ rinv2,
                                              const float* __restrict__ g2a, const float* __restrict__ b2a,
                                              const float* __restrict__ g2b, const float* __restrict__ b2b,
                                              const float* __restrict__ pos1, const float* __restrict__ pos2,
                                              const short* __restrict__ wb,
                                              const float* __restrict__ qb, const float* __restrict__ kvb,
                                              const float* __restrict__ rpb, const float* __restrict__ gammap,
                                              const float* __restrict__ pb,
                                              const float* __restrict__ n2g, const float* __restrict__ n2b,
                                              const float* __restrict__ fb1,
                                              const float* __restrict__ fb2){
    int B = blockIdx.x;
    int hy = (B & 7) | ((B >> 5) & 8);
    int wx = (((B >> 9) & 7) << 1) | ((B >> 3) & 1);
    int b  = (B >> 4) & 15;

    const short* qwb  = wb + OFF_QW;
    const short* kvwb = wb + OFF_KVW;
    const short* pwb  = wb + OFF_PW;
    const short* f1b  = wb + OFF_FW1;
    const short* f2b  = wb + OFF_FW2;

    __shared__ __align__(16) char smem[40464];
    short* bufA = (short*)smem;                    // X1w -> P (wave-private)
    short* bufK = (short*)(smem + 9216);           // K -> Y[t][c] -> XO[t][c]
    short* bufV = (short*)(smem + 18432);          // xn -> V^T[c][t] -> Y^T[c][t]
    short* bufQ = (short*)(smem + 27648);          // X2w -> Q[t][c]
    float* rpb_lds = (float*)(smem + 36864);       // 3600 (dead after head loop)
    float* energyS = (float*)(smem + 36864);       // 1024, aliases rpb
    short* soft_bf = (short*)(smem + 37888);       // 1024, aliases rpb
    // tail aliases:
    float* XOf  = (float*)(smem + 18432);          // 64x66 fp32 (16896 B) over bufV+bufQ
    short* tnb  = (short*)smem;                    // tn bf16 over bufA
    short* h1b  = (short*)(smem + 9216);           // h1 over bufK
    float* sumS = (float*)(smem + 36864);          // 1024
    float* sqS  = (float*)(smem + 37888);          // 1024
    float* muS  = (float*)(smem + 38912);          // 256
    float* rinvS= (float*)(smem + 39168);          // 256

    const int tid = threadIdx.x;
    const int wq = tid >> 6, lane = tid & 63, qd = lane >> 4, col = lane & 15;
    size_t base = (size_t)b * NPLANE;
    #define HWOF(t) ((hy*8 + ((t)>>3))*128 + wx*8 + ((t)&7))

    const float4v zf = {0.f,0.f,0.f,0.f};
    const short8 zero8 = {0,0,0,0,0,0,0,0};

    for (int i = tid; i < 900; i += 256) rpb_lds[i] = rpb[i];

    // ---- P0: load raw x window + LN1 -> xn (bufV slot); lane owns row t ----
    {
        int t = tid & 63, cq = tid >> 6;
        int hw = HWOF(t);
        const float* mup = mu1   + b*64 + 16*cq;
        const float* rvp = rinv1 + b*64 + 16*cq;
        float4v m4[4], r4[4];
        #pragma unroll
        for (int k = 0; k < 4; k++){
            m4[k] = *(const float4v*)(mup + 4*k);
            r4[k] = *(const float4v*)(rvp + 4*k);
        }
        short8 o8[2];
        #pragma unroll
        for (int k = 0; k < 2; k++)
            #pragma unroll
            for (int j = 0; j < 8; j++){
                int jj = 8*k + j;
                float v = x[base + (size_t)(16*cq + jj)*HW + hw];
                o8[k][j] = f2bs((v - m4[jj>>2][jj&3]) * r4[jj>>2][jj&3]);
            }
        *(short8*)&bufV[t*LS + 16*cq]     = o8[0];
        *(short8*)&bufV[t*LS + 16*cq + 8] = o8[1];
    }
    __syncthreads();

    // ---- P1: both convs from xn, fused LN1-affine + LN2 + GELU + pos epilogue ----
    // br0 -> X1w (bufA), br1 -> X2w (bufQ). C[o][t]: o=16wq+4qd+r, t=16jn+col.
    {
        short8 a10 = *(const short8*)&wb[OFF_W1 + (16*wq + col)*64 + 8*qd];
        short8 a11 = *(const short8*)&wb[OFF_W1 + (16*wq + col)*64 + 32 + 8*qd];
        short8 a20 = *(const short8*)&wb[OFF_W2 + (16*wq + col)*64 + 8*qd];
        short8 a21 = *(const short8*)&wb[OFF_W2 + (16*wq + col)*64 + 32 + 8*qd];
        float cb1v[4], rs1v[4], m2a[4], rv2a[4];
        float cb2v[4], rs2v[4], m2b[4], rv2b[4];
        #pragma unroll
        for (int r = 0; r < 4; r++){
            int o = 16*wq + 4*qd + r;
            cb1v[r] = cb1[o]; rs1v[r] = rowsum[o];
            m2a[r] = mu2[b*64 + o]; rv2a[r] = rinv2[b*64 + o];
            cb2v[r] = cb2[o]; rs2v[r] = rowsum[64 + o];
            m2b[r] = mu2[1024 + b*64 + o]; rv2b[r] = rinv2[1024 + b*64 + o];
        }
        #pragma unroll
        for (int jn = 0; jn < 4; jn++){
            int t = 16*jn + col; int hw = HWOF(t);
            short8 bx0 = *(const short8*)&bufV[t*LS + 8*qd];
            short8 bx1 = *(const short8*)&bufV[t*LS + 32 + 8*qd];
            // branch 0
            {
                float4v acc = zf;
                acc = MFMA(a10, bx0, acc);
                acc = MFMA(a11, bx1, acc);
                float gl = g1a[hw], bl = b1a[hw], gg = g2a[hw], bo = b2a[hw];
                float4v p4 = *(const float4v*)(pos1 + t*64 + 16*wq + 4*qd);
                short4v pk;
                #pragma unroll
                for (int r = 0; r < 4; r++){
                    float v = gl*acc[r] + bl*rs1v[r] + cb1v[r];
                    float z = (v - m2a[r]) * rv2a[r] * gg + bo;
                    pk[r] = f2bs(gelu_exact(z) + p4[r]);
                }
                *(short4v*)&bufA[t*LS + 16*wq + 4*qd] = pk;
            }
            // branch 1
            {
                float4v acc = zf;
                acc = MFMA(a20, bx0, acc);
                acc = MFMA(a21, bx1, acc);
                float gl = g1b[hw], bl = b1b[hw], gg = g2b[hw], bo = b2b[hw];
                float4v p4 = *(const float4v*)(pos2 + t*64 + 16*wq + 4*qd);
                short4v pk;
                #pragma unroll
                for (int r = 0; r < 4; r++){
                    float v = gl*acc[r] + bl*rs2v[r] + cb2v[r];
                    float z = (v - m2b[r]) * rv2b[r] * gg + bo;
                    pk[r] = f2bs(gelu_exact(z) + p4[r]);
                }
                *(short4v*)&bufQ[t*LS + 16*wq + 4*qd] = pk;
            }
        }
    }
    __syncthreads();

    // ---- P2: V^T and K from X2w (bufQ); xn (bufV) dead -> V^T target ----
    {
        short8 ax0 = *(const short8*)&bufQ[(16*wq + col)*LS + 8*qd];
        short8 ax1 = *(const short8*)&bufQ[(16*wq + col)*LS + 32 + 8*qd];
        // V^T: C[t][c] -> write bufV[c][t] packed
        #pragma unroll
        for (int jn = 0; jn < 4; jn++){
            int c = 16*jn + col;
            short8 wv0 = *(const short8*)&kvwb[(64 + c)*64 + 8*qd];
            short8 wv1 = *(const short8*)&kvwb[(64 + c)*64 + 32 + 8*qd];
            float4v acc = zf;
            acc = MFMA(ax0, wv0, acc);
            acc = MFMA(ax1, wv1, acc);
            float bv = kvb[64 + c];
            short4v pk;
            #pragma unroll
            for (int r = 0; r < 4; r++) pk[r] = f2bs(acc[r] + bv);
            *(short4v*)&bufV[c*LS + 16*wq + 4*qd] = pk;
        }
        // K: C[c][t] -> write bufK[t][c] packed
        short8 a0 = *(const short8*)&kvwb[(16*wq + col)*64 + 8*qd];
        short8 a1 = *(const short8*)&kvwb[(16*wq + col)*64 + 32 + 8*qd];
        float kbr[4];
        #pragma unroll
        for (int r = 0; r < 4; r++) kbr[r] = kvb[16*wq + 4*qd + r];
        #pragma unroll
        for (int jn = 0; jn < 4; jn++){
            int t = 16*jn + col;
            short8 bx0 = *(const short8*)&bufQ[t*LS + 8*qd];
            short8 bx1 = *(const short8*)&bufQ[t*LS + 32 + 8*qd];
            float4v acc = zf;
            acc = MFMA(a0, bx0, acc);
            acc = MFMA(a1, bx1, acc);
            short4v pk;
            #pragma unroll
            for (int r = 0; r < 4; r++) pk[r] = f2bs(acc[r] + kbr[r]);
            *(short4v*)&bufK[t*LS + 16*wq + 4*qd] = pk;
        }
    }
    __syncthreads();

    // ---- P3: Q from X1w (bufA) -> bufQ (X2w dead); capture X1w residual ----
    {
        short8 a0 = *(const short8*)&qwb[(16*wq + col)*64 + 8*qd];
        short8 a1 = *(const short8*)&qwb[(16*wq + col)*64 + 32 + 8*qd];
        float qbr[4];
        #pragma unroll
        for (int r = 0; r < 4; r++) qbr[r] = qb[16*wq + 4*qd + r];
        #pragma unroll
        for (int jn = 0; jn < 4; jn++){
            int t = 16*jn + col;
            short8 bx0 = *(const short8*)&bufA[t*LS + 8*qd];
            short8 bx1 = *(const short8*)&bufA[t*LS + 32 + 8*qd];
            float4v acc = zf;
            acc = MFMA(a0, bx0, acc);
            acc = MFMA(a1, bx1, acc);
            short4v pk;
            #pragma unroll
            for (int r = 0; r < 4; r++) pk[r] = f2bs((acc[r] + qbr[r]) * 0.25f);
            *(short4v*)&bufQ[t*LS + 16*wq + 4*qd] = pk;
        }
    }
    short4v xreg[4];
    #pragma unroll
    for (int h = 0; h < 4; h++){
        short4v xr;
        #pragma unroll
        for (int r = 0; r < 4; r++)
            xr[r] = bufA[(16*wq + 4*qd + r)*LS + 16*h + col];
        xreg[h] = xr;
    }
    __syncthreads();

    // rel-pos bias indices for S^T mapping: t = 16wq+col (fixed), u = 16jn+4qd+r
    int idx_t[4][4];
    {
        int t = 16*wq + col, ty = t >> 3, tx = t & 7;
        #pragma unroll
        for (int jn = 0; jn < 4; jn++)
            #pragma unroll
            for (int r = 0; r < 4; r++){
                int u = 16*jn + 4*qd + r;
                idx_t[jn][r] = (ty - (u>>3) + 7)*15 + (tx - (u&7) + 7);
            }
    }

    // ---- head loop: S^T -> thread-local softmax -> P (wave-private) -> PV -> Y/Y^T ----
    for (int h = 0; h < 4; h++){
        short8 bq = *(const short8*)&bufQ[(16*wq + col)*LS + h*16 + (qd & 1)*8];
        float pr[4][4];
        #pragma unroll
        for (int jn = 0; jn < 4; jn++){
            short8 ak = *(const short8*)&bufK[(16*jn + col)*LS + h*16 + (qd & 1)*8];
            if (qd >= 2) ak = zero8;
            float4v acc = MFMA(ak, bq, zf);
            #pragma unroll
            for (int r = 0; r < 4; r++)
                pr[jn][r] = acc[r] + rpb_lds[idx_t[jn][r]*4 + h];
        }
        float m = pr[0][0];
        #pragma unroll
        for (int jn = 0; jn < 4; jn++)
            #pragma unroll
            for (int r = 0; r < 4; r++) m = fmaxf(m, pr[jn][r]);
        m = fmaxf(m, __shfl_xor(m, 16));
        m = fmaxf(m, __shfl_xor(m, 32));
        float s = 0.f;
        #pragma unroll
        for (int jn = 0; jn < 4; jn++)
            #pragma unroll
            for (int r = 0; r < 4; r++){ pr[jn][r] = __expf(pr[jn][r] - m); s += pr[jn][r]; }
        s += __shfl_xor(s, 16);
        s += __shfl_xor(s, 32);
        float rc = 1.f / s;
        #pragma unroll
        for (int jn = 0; jn < 4; jn++){
            short4v pk;
            #pragma unroll
            for (int r = 0; r < 4; r++) pk[r] = f2bs(pr[jn][r] * rc);
            *(short4v*)&bufA[(16*wq + col)*LS + 16*jn + 4*qd] = pk;
        }
        short8 ap0 = *(const short8*)&bufA[(16*wq + col)*LS + 8*qd];
        short8 ap1 = *(const short8*)&bufA[(16*wq + col)*LS + 32 + 8*qd];
        short8 bv0 = *(const short8*)&bufV[(h*16 + col)*LS + 8*qd];
        short8 bv1 = *(const short8*)&bufV[(h*16 + col)*LS + 32 + 8*qd];
        float4v acc_o = zf;
        acc_o = MFMA(ap0, bv0, acc_o);
        acc_o = MFMA(ap1, bv1, acc_o);
        __syncthreads();          // all waves done reading V rows of this head
        short4v ot;
        #pragma unroll
        for (int r = 0; r < 4; r++) ot[r] = f2bs(acc_o[r]);
        *(short4v*)&bufV[(h*16 + col)*LS + 16*wq + 4*qd] = ot;   // Y^T
        #pragma unroll
        for (int r = 0; r < 4; r++)
            bufK[(16*wq + 4*qd + r)*LS + h*16 + col] = ot[r];    // Y
    }
    __syncthreads();

    // ---- energy = Y Y^T (16x16, K=256) ----
    {
        float4v acc_e = zf;
        #pragma unroll
        for (int h = 0; h < 4; h++){
            short8 f0 = *(const short8*)&bufV[(h*16 + col)*LS + 8*qd];
            short8 f1 = *(const short8*)&bufV[(h*16 + col)*LS + 32 + 8*qd];
            acc_e = MFMA(f0, f0, acc_e);
            acc_e = MFMA(f1, f1, acc_e);
        }
        if (wq == 0){
            #pragma unroll
            for (int r = 0; r < 4; r++) energyS[(4*qd + r)*16 + col] = acc_e[r];
        }
    }
    __syncthreads();
    if (tid < 16){
        int i = tid; float m = -1e30f;
        for (int j = 0; j < 16; j++) m = fmaxf(m, energyS[i*16 + j]);
        float s = 0.f; float e[16];
        for (int j = 0; j < 16; j++){ e[j] = __expf(energyS[i*16 + j] - m); s += e[j]; }
        float rc = 1.f / s;
        for (int j = 0; j < 16; j++) soft_bf[i*32 + j] = f2bs(e[j] * rc);
        for (int j = 0; j < 16; j++) soft_bf[i*32 + 16 + j] = 0;
    }
    __syncthreads();

    // ---- lam + assemble XO -> bufK (overwrite Y slots, wave-private rows) ----
    {
        float gam = gammap[0];
        short8 asf = *(const short8*)&soft_bf[col*32 + 8*qd];
        #pragma unroll
        for (int h = 0; h < 4; h++){
            short8 ay = *(const short8*)&bufK[(16*wq + col)*LS + 16*h + (qd & 1)*8];
            float4v acc = MFMA(ay, asf, zf);
            short4v xv = xreg[h];
            #pragma unroll
            for (int r = 0; r < 4; r++){
                int ro = (16*wq + 4*qd + r)*LS + 16*h + col;
                float ot = bs2f(bufK[ro]);
                float qv = bs2f(bufQ[ro]);
                float xo = gam*acc[r] + ot + qv + bs2f(xv[r]);
                bufK[ro] = f2bs(xo);
            }
        }
    }
    __syncthreads();

    // ---- proj: C[c][t] -> XOf[t*66+c] packed f2 ----
    {
        short8 a0 = *(const short8*)&pwb[(16*wq + col)*64 + 8*qd];
        short8 a1 = *(const short8*)&pwb[(16*wq + col)*64 + 32 + 8*qd];
        float pbr[4];
        #pragma unroll
        for (int r = 0; r < 4; r++) pbr[r] = pb[16*wq + 4*qd + r];
        #pragma unroll
        for (int jn = 0; jn < 4; jn++){
            int t = 16*jn + col;
            short8 bx0 = *(const short8*)&bufK[t*LS + 8*qd];
            short8 bx1 = *(const short8*)&bufK[t*LS + 32 + 8*qd];
            float4v acc = zf;
            acc = MFMA(a0, bx0, acc);
            acc = MFMA(a1, bx1, acc);
            float2v w0 = {acc[0]+pbr[0], acc[1]+pbr[1]};
            float2v w1 = {acc[2]+pbr[2], acc[3]+pbr[3]};
            *(float2v*)&XOf[t*66 + 16*wq + 4*qd]     = w0;
            *(float2v*)&XOf[t*66 + 16*wq + 4*qd + 2] = w1;
        }
    }
    __syncthreads();

    // ================= fused channel-MLP =================
    {
        int p = tid & 63, qg = tid >> 6;
        float s = 0.f, ss = 0.f;
        #pragma unroll
        for (int j = 0; j < 8; j++){
            float2v v = *(const float2v*)&XOf[p*66 + qg*16 + 2*j];
            s += v[0]+v[1]; ss += v[0]*v[0] + v[1]*v[1];
        }
        sumS[qg*64 + p] = s; sqS[qg*64 + p] = ss;
    }
    __syncthreads();
    if (tid < 64){
        float s  = sumS[tid] + sumS[64+tid] + sumS[128+tid] + sumS[192+tid];
        float ss = sqS[tid]  + sqS[64+tid]  + sqS[128+tid]  + sqS[192+tid];
        float m = s * (1.f/64.f);
        float var = ss * (1.f/64.f) - m*m;
        muS[tid] = m; rinvS[tid] = rsqrtf(var + EPS);
    }
    __syncthreads();
    // tn -> tnb (bf16, over bufA), packed b128 writes
    {
        int p = tid & 63, qg = tid >> 6;
        float m = muS[p], rv = rinvS[p];
        short8 o8[2];
        #pragma unroll
        for (int k = 0; k < 2; k++)
            #pragma unroll
            for (int j = 0; j < 8; j++){
                int c = qg*16 + k*8 + j;
                o8[k][j] = f2bs((XOf[p*66 + c] - m) * rv * n2g[c] + n2b[c]);
            }
        *(short8*)&tnb[p*LS + qg*16]     = o8[0];
        *(short8*)&tnb[p*LS + qg*16 + 8] = o8[1];
    }
    __syncthreads();
    // GEMM1: C[j][t]; h1b[t][j] packed
    {
        short8 a0 = *(const short8*)&f1b[(16*wq + col)*64 + 8*qd];
        short8 a1 = *(const short8*)&f1b[(16*wq + col)*64 + 32 + 8*qd];
        float fbr[4];
        #pragma unroll
        for (int r = 0; r < 4; r++) fbr[r] = fb1[16*wq + 4*qd + r];
        #pragma unroll
        for (int jn = 0; jn < 4; jn++){
            int t = 16*jn + col;
            short8 bx0 = *(const short8*)&tnb[t*LS + 8*qd];
            short8 bx1 = *(const short8*)&tnb[t*LS + 32 + 8*qd];
            float4v acc = zf;
            acc = MFMA(a0, bx0, acc);
            acc = MFMA(a1, bx1, acc);
            short4v pk;
            #pragma unroll
            for (int r = 0; r < 4; r++) pk[r] = f2bs(gelu_exact(acc[r] + fbr[r]));
            *(short4v*)&h1b[t*LS + 16*wq + 4*qd] = pk;
        }
    }
    __syncthreads();
    // GEMM2: out = xo + h1 @ W2^T + fb2 -> global planar fp32
    {
        short8 a0 = *(const short8*)&h1b[(16*wq + col)*LS + 8*qd];
        short8 a1 = *(const short8*)&h1b[(16*wq + col)*LS + 32 + 8*qd];
        #pragma unroll
        for (int jn = 0; jn < 4; jn++){
            int c2 = 16*jn + col;
            short8 f0 = *(const short8*)&f2b[c2*64 + 8*qd];
            short8 f1 = *(const short8*)&f2b[c2*64 + 32 + 8*qd];
            float4v acc = zf;
            acc = MFMA(a0, f0, acc);
            acc = MFMA(a1, f1, acc);
            float bv = fb2[c2];
            float4v ov;
            #pragma unroll
            for (int r = 0; r < 4; r++)
                ov[r] = acc[r] + bv + XOf[(16*wq + 4*qd + r)*66 + c2];
            int t0 = 16*wq + 4*qd;
            *(float4v*)(outp + base + (size_t)c2*HW + HWOF(t0)) = ov;
        }
    }
    #undef HWOF
}

extern "C" void kernel_launch(void* const* d_in, const int* in_sizes, int n_in,
                              void* d_out, int out_size, void* d_ws, size_t ws_size,
                              hipStream_t stream){
    const float* x        = (const float*)d_in[0];
    const float* l1_g1    = (const float*)d_in[1];
    const float* l1_b1    = (const float*)d_in[2];
    const float* l1_cw    = (const float*)d_in[3];
    const float* l1_cb    = (const float*)d_in[4];
    const float* l1_g2    = (const float*)d_in[5];
    const float* l1_b2    = (const float*)d_in[6];
    const float* l2_g1    = (const float*)d_in[7];
    const float* l2_b1    = (const float*)d_in[8];
    const float* l2_cw    = (const float*)d_in[9];
    const float* l2_cb    = (const float*)d_in[10];
    const float* l2_g2    = (const float*)d_in[11];
    const float* l2_b2    = (const float*)d_in[12];
    const float* pos1     = (const float*)d_in[13];
    const float* pos2     = (const float*)d_in[14];
    const float* q_w      = (const float*)d_in[15];
    const float* q_b      = (const float*)d_in[16];
    const float* kv_w     = (const float*)d_in[17];
    const float* kv_b     = (const float*)d_in[18];
    const float* rpb      = (const float*)d_in[19];
    const float* gamma    = (const float*)d_in[20];
    const float* proj_w   = (const float*)d_in[21];
    const float* proj_b   = (const float*)d_in[22];
    const float* norm2_g  = (const float*)d_in[23];
    const float* norm2_b  = (const float*)d_in[24];
    const float* fc1_w    = (const float*)d_in[25];
    const float* fc1_b    = (const float*)d_in[26];
    const float* fc2_w    = (const float*)d_in[27];
    const float* fc2_b    = (const float*)d_in[28];

    float* out = (float*)d_out;                 // final output only (written once)

    float* partS = (float*)d_ws;                // 2048*256 floats (2 MB)
    float* partQ = partS + (size_t)2048*256;    // 2 MB
    float* mu1   = partQ + (size_t)2048*256;    // 1024
    float* rinv1 = mu1 + 1024;                  // 1024
    float* mu2   = rinv1 + 1024;                // 2048
    float* rinv2 = mu2 + 2048;                  // 2048
    float* rowsumG = rinv2 + 2048;              // 128
    short* wbuf  = (short*)(rowsumG + 128);     // 32768 shorts

    k_pre  <<<1033, 256, 0, stream>>>(x, mu1, rinv1,
                                      l1_cw, l2_cw, q_w, kv_w, proj_w, fc1_w, fc2_w,
                                      wbuf, rowsumG);
    k_conv <<<4096, 256, 0, stream>>>(x, mu1, rinv1,
                                      l1_g1, l1_b1, l1_cb,
                                      l2_g1, l2_b1, l2_cb,
                                      wbuf, rowsumG,
                                      partS, partQ);
    k_fin  <<<512, 256, 0, stream>>>(partS, partQ, mu2, rinv2);
    k_attn <<<4096, 256, 0, stream>>>(x, out, mu1, rinv1, rowsumG,
                                      l1_cb, l2_cb,
                                      l1_g1, l1_b1, l2_g1, l2_b1,
                                      mu2, rinv2,
                                      l1_g2, l1_b2, l2_g2, l2_b2,
                                      pos1, pos2, wbuf, q_b, kv_b,
                                      rpb, gamma, proj_b,
                                      norm2_g, norm2_b, fc1_b, fc2_b);
}

// Round 5
// 316.537 us; speedup vs baseline: 1.7905x; 1.0202x over previous
//
#include <hip/hip_runtime.h>
#include <hip/hip_bf16.h>

typedef __hip_bfloat16 bf16;
typedef __attribute__((ext_vector_type(8))) short short8;
typedef __attribute__((ext_vector_type(4))) short short4v;
typedef __attribute__((ext_vector_type(4))) float float4v;
typedef __attribute__((ext_vector_type(2))) float float2v;

__device__ __forceinline__ short f2bs(float f){
    union { bf16 h; short s; } u; u.h = __float2bfloat16(f); return u.s;
}
__device__ __forceinline__ float bs2f(short s){
    return __uint_as_float(((unsigned)(unsigned short)s) << 16);
}
// Branch-free exact-GELU via Abramowitz-Stegun 7.1.26 erf (|eps|~1.5e-7 + ~1e-5 rcp;
// both far below bf16 ulp, so bf16-rounded outputs are unchanged).
__device__ __forceinline__ float gelu_exact(float x){
    float ax = fabsf(x) * 0.70710678118654752440f;
    float t  = __builtin_amdgcn_rcpf(fmaf(0.3275911f, ax, 1.0f));
    float poly = t*fmaf(t, fmaf(t, fmaf(t, fmaf(t, 1.061405429f, -1.453152027f),
                                 1.421413741f), -0.284496736f), 0.254829592f);
    float e = __expf(-ax*ax);
    float erfp = fmaf(-poly, e, 1.0f);          // erf(|x|/sqrt2)
    float er = copysignf(erfp, x);
    return 0.5f * x * (1.0f + er);
}
#define MFMA(a,b,c) __builtin_amdgcn_mfma_f32_16x16x32_bf16((a),(b),(c),0,0,0)

#define HW 16384
#define NPLANE 1048576
#define EPS 1e-5f
#define LS 72             // LDS row stride in bf16 (144 B)

// wb layout (shorts): 0:w1b 4096:w2b 8192:qwb 12288:kvwb(8192) 20480:pwb 24576:fw1b 28672:fw2b
#define OFF_W1   0
#define OFF_W2   4096
#define OFF_QW   8192
#define OFF_KVW  12288
#define OFF_PW   20480
#define OFF_FW1  24576
#define OFF_FW2  28672

// ---------------- Kernel 1: LN1 stats (blocks 0..1023) + weight prep (1024..1032) ----------------
__global__ __launch_bounds__(256) void k_pre(const float* __restrict__ x,
                                             float* __restrict__ mu,
                                             float* __restrict__ rinv,
                                             const float* __restrict__ w1, const float* __restrict__ w2,
                                             const float* __restrict__ qw, const float* __restrict__ kvw,
                                             const float* __restrict__ pw, const float* __restrict__ fw1,
                                             const float* __restrict__ fw2,
                                             short* __restrict__ wb, float* __restrict__ rowsum){
    int bi = blockIdx.x;
    int tid = threadIdx.x;
    if (bi < 1024){
        const float* p = x + (size_t)bi * HW;
        float s = 0.f, ss = 0.f;
        for (int i = tid; i < HW/4; i += 256){
            float4v v = *(const float4v*)(p + i*4);
            #pragma unroll
            for (int k = 0; k < 4; k++){ s += v[k]; ss += v[k]*v[k]; }
        }
        __shared__ float rs[256], rss[256];
        rs[tid] = s; rss[tid] = ss; __syncthreads();
        for (int st = 128; st > 0; st >>= 1){
            if (tid < st){ rs[tid] += rs[tid+st]; rss[tid] += rss[tid+st]; }
            __syncthreads();
        }
        if (tid == 0){
            float m = rs[0] * (1.f/HW);
            float v = rss[0] * (1.f/HW) - m*m;
            mu[bi] = m; rinv[bi] = rsqrtf(v + EPS);
        }
    } else if (bi < 1032){
        int wi = bi - 1024;
        const float* src = wi==0?w1: wi==1?w2: wi==2?qw: wi==3?kvw: wi==4?(kvw+4096): wi==5?pw: wi==6?fw1: fw2;
        short* dst = wb + wi*4096;
        int base = tid*16;
        short8 o8[2];
        #pragma unroll
        for (int k = 0; k < 2; k++){
            float4v v0 = *(const float4v*)(src + base + 8*k);
            float4v v1 = *(const float4v*)(src + base + 8*k + 4);
            #pragma unroll
            for (int j = 0; j < 4; j++){ o8[k][j] = f2bs(v0[j]); o8[k][4+j] = f2bs(v1[j]); }
        }
        *(short8*)&dst[base]     = o8[0];
        *(short8*)&dst[base + 8] = o8[1];
    } else {
        if (tid < 128){
            int br = tid >> 6, o = tid & 63;
            const float* W = br ? w2 : w1;
            float s = 0.f;
            for (int c = 0; c < 64; c++) s += W[o*64 + c];
            rowsum[br*64 + o] = s;
        }
    }
}

// ---------------- Kernel 2: LN1 + 1x1 conv stats, 4 tiles per block ----------------
// 1024 blocks = 16 b x 64 chunks; per-block consts loaded once; register accumulation
// across tiles; ONE shuffle-reduce + partial store per block.
__global__ __launch_bounds__(256, 4) void k_conv(const float* __restrict__ x,
                                              const float* __restrict__ mu,
                                              const float* __restrict__ rinv,
                                              const float* __restrict__ g1a, const float* __restrict__ b1a,
                                              const float* __restrict__ cb1,
                                              const float* __restrict__ g1b, const float* __restrict__ b1b,
                                              const float* __restrict__ cb2,
                                              const short* __restrict__ wb,
                                              const float* __restrict__ rowsum,
                                              float* __restrict__ partS, float* __restrict__ partQ){
    int blk = blockIdx.x;
    int b = blk >> 6; int chunk = blk & 63;
    __shared__ __align__(16) short xn_bf[64*LS];
    const int tid = threadIdx.x;
    const int wq = tid >> 6, lane = tid & 63, qd = lane >> 4, col = lane & 15;
    const float4v zf = {0.f,0.f,0.f,0.f};
    const int p = tid & 63, cq = tid >> 6;

    float4v m4[4], r4[4];
    #pragma unroll
    for (int k = 0; k < 4; k++){
        m4[k] = *(const float4v*)(mu   + b*64 + 16*cq + 4*k);
        r4[k] = *(const float4v*)(rinv + b*64 + 16*cq + 4*k);
    }
    short8 a10 = *(const short8*)&wb[OFF_W1 + (16*wq + col)*64 + 8*qd];
    short8 a11 = *(const short8*)&wb[OFF_W1 + (16*wq + col)*64 + 32 + 8*qd];
    short8 a20 = *(const short8*)&wb[OFF_W2 + (16*wq + col)*64 + 8*qd];
    short8 a21 = *(const short8*)&wb[OFF_W2 + (16*wq + col)*64 + 32 + 8*qd];
    float cb1v[4], rs1v[4], cb2v[4], rs2v[4];
    #pragma unroll
    for (int r = 0; r < 4; r++){
        int o = 16*wq + 4*qd + r;
        cb1v[r] = cb1[o]; rs1v[r] = rowsum[o];
        cb2v[r] = cb2[o]; rs2v[r] = rowsum[64 + o];
    }
    float sa[2][4]  = {{0.f,0.f,0.f,0.f},{0.f,0.f,0.f,0.f}};
    float ssa[2][4] = {{0.f,0.f,0.f,0.f},{0.f,0.f,0.f,0.f}};

    for (int tl = 0; tl < 4; tl++){
        int hw0 = chunk*256 + tl*64;
        {
            const float* xb = x + (size_t)(b*64 + 16*cq)*HW + hw0 + p;
            short8 o8[2];
            #pragma unroll
            for (int k = 0; k < 2; k++)
                #pragma unroll
                for (int j = 0; j < 8; j++){
                    int jj = 8*k + j;
                    float v = xb[(size_t)jj*HW];
                    o8[k][j] = f2bs((v - m4[jj>>2][jj&3]) * r4[jj>>2][jj&3]);
                }
            *(short8*)&xn_bf[p*LS + 16*cq]     = o8[0];
            *(short8*)&xn_bf[p*LS + 16*cq + 8] = o8[1];
        }
        __syncthreads();
        #pragma unroll
        for (int jn = 0; jn < 4; jn++){
            short8 bx0 = *(const short8*)&xn_bf[(16*jn + col)*LS + 8*qd];
            short8 bx1 = *(const short8*)&xn_bf[(16*jn + col)*LS + 32 + 8*qd];
            int hw = hw0 + 16*jn + col;
            {
                float4v acc = zf;
                acc = MFMA(a10, bx0, acc);
                acc = MFMA(a11, bx1, acc);
                float gl = g1a[hw], bl = b1a[hw];
                #pragma unroll
                for (int r = 0; r < 4; r++){
                    float v = gl*acc[r] + bl*rs1v[r] + cb1v[r];
                    sa[0][r] += v; ssa[0][r] += v*v;
                }
            }
            {
                float4v acc = zf;
                acc = MFMA(a20, bx0, acc);
                acc = MFMA(a21, bx1, acc);
                float gl = g1b[hw], bl = b1b[hw];
                #pragma unroll
                for (int r = 0; r < 4; r++){
                    float v = gl*acc[r] + bl*rs2v[r] + cb2v[r];
                    sa[1][r] += v; ssa[1][r] += v*v;
                }
            }
        }
        __syncthreads();
    }

    #pragma unroll
    for (int br = 0; br < 2; br++)
        #pragma unroll
        for (int r = 0; r < 4; r++){
            float s = sa[br][r], ss = ssa[br][r];
            s += __shfl_xor(s, 1); ss += __shfl_xor(ss, 1);
            s += __shfl_xor(s, 2); ss += __shfl_xor(ss, 2);
            s += __shfl_xor(s, 4); ss += __shfl_xor(ss, 4);
            s += __shfl_xor(s, 8); ss += __shfl_xor(ss, 8);
            if (col == 0){
                int o = 16*wq + 4*qd + r;
                size_t pi = ((size_t)(br*16 + b)*64 + o)*64 + chunk;
                partS[pi] = s; partQ[pi] = ss;
            }
        }
}

// ---------------- Kernel 3: reduce LN2 partials (2048 rows x 64 chunks), wave-per-row ----------------
__global__ __launch_bounds__(256) void k_fin(const float* __restrict__ partS,
                                             const float* __restrict__ partQ,
                                             float* __restrict__ mu2,
                                             float* __restrict__ rinv2){
    int row = blockIdx.x*4 + (threadIdx.x >> 6);   // 0..2047
    int lane = threadIdx.x & 63;
    float s  = partS[(size_t)row*64 + lane];
    float ss = partQ[(size_t)row*64 + lane];
    #pragma unroll
    for (int st = 1; st < 64; st <<= 1){
        s  += __shfl_xor(s,  st);
        ss += __shfl_xor(ss, st);
    }
    if (lane == 0){
        float m = s * (1.f/HW);
        float v = ss * (1.f/HW) - m*m;
        mu2[row] = m; rinv2[row] = rsqrtf(v + EPS);
    }
}

// ---------------- Kernel 4: full fused window pipeline ----------------
__global__ __launch_bounds__(256, 4) void k_attn(const float* __restrict__ x, float* __restrict__ outp,
                                              const float* __restrict__ mu1, const float* __restrict__ rinv1,
                                              const float* __restrict__ rowsum,
                                              const float* __restrict__ cb1, const float* __restrict__ cb2,
                                              const float* __restrict__ g1a, const float* __restrict__ b1a,
                                              const float* __restrict__ g1b, const float* __restrict__ b1b,
                                              const float* __restrict__ mu2, const float* __restrict__ rinv2,
                                              const float* __restrict__ g2a, const float* __restrict__ b2a,
                                              const float* __restrict__ g2b, const float* __restrict__ b2b,
                                              const float* __restrict__ pos1, const float* __restrict__ pos2,
                                              const short* __restrict__ wb,
                                              const float* __restrict__ qb, const float* __restrict__ kvb,
                                              const float* __restrict__ rpb, const float* __restrict__ gammap,
                                              const float* __restrict__ pb,
                                              const float* __restrict__ n2g, const float* __restrict__ n2b,
                                              const float* __restrict__ fb1,
                                              const float* __restrict__ fb2){
    int B = blockIdx.x;
    int hy = (B & 7) | ((B >> 5) & 8);
    int wx = (((B >> 9) & 7) << 1) | ((B >> 3) & 1);
    int b  = (B >> 4) & 15;

    const short* qwb  = wb + OFF_QW;
    const short* kvwb = wb + OFF_KVW;
    const short* pwb  = wb + OFF_PW;
    const short* f1b  = wb + OFF_FW1;
    const short* f2b  = wb + OFF_FW2;

    __shared__ __align__(16) char smem[40464];
    short* bufA = (short*)smem;                    // X1w -> P (wave-private)
    short* bufK = (short*)(smem + 9216);           // K -> Y[t][c] -> XO[t][c]
    short* bufV = (short*)(smem + 18432);          // xn -> V^T[c][t] -> Y^T[c][t]
    short* bufQ = (short*)(smem + 27648);          // X2w -> Q[t][c]
    float* rpb_lds = (float*)(smem + 36864);       // 3600 (dead after head loop)
    float* energyS = (float*)(smem + 36864);       // 1024, aliases rpb
    short* soft_bf = (short*)(smem + 37888);       // 1024, aliases rpb
    // tail aliases:
    float* XOf  = (float*)(smem + 18432);          // 64x66 fp32 (16896 B) over bufV+bufQ
    short* tnb  = (short*)smem;                    // tn bf16 over bufA
    short* h1b  = (short*)(smem + 9216);           // h1 over bufK
    float* sumS = (float*)(smem + 36864);          // 1024
    float* sqS  = (float*)(smem + 37888);          // 1024
    float* muS  = (float*)(smem + 38912);          // 256
    float* rinvS= (float*)(smem + 39168);          // 256

    const int tid = threadIdx.x;
    const int wq = tid >> 6, lane = tid & 63, qd = lane >> 4, col = lane & 15;
    size_t base = (size_t)b * NPLANE;
    #define HWOF(t) ((hy*8 + ((t)>>3))*128 + wx*8 + ((t)&7))

    const float4v zf = {0.f,0.f,0.f,0.f};
    const short8 zero8 = {0,0,0,0,0,0,0,0};

    for (int i = tid; i < 900; i += 256) rpb_lds[i] = rpb[i];

    // ---- P0: load raw x window + LN1 -> xn (bufV slot); lane owns row t ----
    {
        int t = tid & 63, cq = tid >> 6;
        int hw = HWOF(t);
        const float* mup = mu1   + b*64 + 16*cq;
        const float* rvp = rinv1 + b*64 + 16*cq;
        float4v m4[4], r4[4];
        #pragma unroll
        for (int k = 0; k < 4; k++){
            m4[k] = *(const float4v*)(mup + 4*k);
            r4[k] = *(const float4v*)(rvp + 4*k);
        }
        short8 o8[2];
        #pragma unroll
        for (int k = 0; k < 2; k++)
            #pragma unroll
            for (int j = 0; j < 8; j++){
                int jj = 8*k + j;
                float v = x[base + (size_t)(16*cq + jj)*HW + hw];
                o8[k][j] = f2bs((v - m4[jj>>2][jj&3]) * r4[jj>>2][jj&3]);
            }
        *(short8*)&bufV[t*LS + 16*cq]     = o8[0];
        *(short8*)&bufV[t*LS + 16*cq + 8] = o8[1];
    }
    __syncthreads();

    // ---- P1: both convs from xn, fused LN1-affine + LN2 + GELU + pos epilogue ----
    {
        short8 a10 = *(const short8*)&wb[OFF_W1 + (16*wq + col)*64 + 8*qd];
        short8 a11 = *(const short8*)&wb[OFF_W1 + (16*wq + col)*64 + 32 + 8*qd];
        short8 a20 = *(const short8*)&wb[OFF_W2 + (16*wq + col)*64 + 8*qd];
        short8 a21 = *(const short8*)&wb[OFF_W2 + (16*wq + col)*64 + 32 + 8*qd];
        float cb1v[4], rs1v[4], m2a[4], rv2a[4];
        float cb2v[4], rs2v[4], m2b[4], rv2b[4];
        #pragma unroll
        for (int r = 0; r < 4; r++){
            int o = 16*wq + 4*qd + r;
            cb1v[r] = cb1[o]; rs1v[r] = rowsum[o];
            m2a[r] = mu2[b*64 + o]; rv2a[r] = rinv2[b*64 + o];
            cb2v[r] = cb2[o]; rs2v[r] = rowsum[64 + o];
            m2b[r] = mu2[1024 + b*64 + o]; rv2b[r] = rinv2[1024 + b*64 + o];
        }
        #pragma unroll
        for (int jn = 0; jn < 4; jn++){
            int t = 16*jn + col; int hw = HWOF(t);
            short8 bx0 = *(const short8*)&bufV[t*LS + 8*qd];
            short8 bx1 = *(const short8*)&bufV[t*LS + 32 + 8*qd];
            {
                float4v acc = zf;
                acc = MFMA(a10, bx0, acc);
                acc = MFMA(a11, bx1, acc);
                float gl = g1a[hw], bl = b1a[hw], gg = g2a[hw], bo = b2a[hw];
                float4v p4 = *(const float4v*)(pos1 + t*64 + 16*wq + 4*qd);
                short4v pk;
                #pragma unroll
                for (int r = 0; r < 4; r++){
                    float v = gl*acc[r] + bl*rs1v[r] + cb1v[r];
                    float z = (v - m2a[r]) * rv2a[r] * gg + bo;
                    pk[r] = f2bs(gelu_exact(z) + p4[r]);
                }
                *(short4v*)&bufA[t*LS + 16*wq + 4*qd] = pk;
            }
            {
                float4v acc = zf;
                acc = MFMA(a20, bx0, acc);
                acc = MFMA(a21, bx1, acc);
                float gl = g1b[hw], bl = b1b[hw], gg = g2b[hw], bo = b2b[hw];
                float4v p4 = *(const float4v*)(pos2 + t*64 + 16*wq + 4*qd);
                short4v pk;
                #pragma unroll
                for (int r = 0; r < 4; r++){
                    float v = gl*acc[r] + bl*rs2v[r] + cb2v[r];
                    float z = (v - m2b[r]) * rv2b[r] * gg + bo;
                    pk[r] = f2bs(gelu_exact(z) + p4[r]);
                }
                *(short4v*)&bufQ[t*LS + 16*wq + 4*qd] = pk;
            }
        }
    }
    __syncthreads();

    // ---- P2: V^T and K from X2w (bufQ); xn (bufV) dead -> V^T target ----
    {
        short8 ax0 = *(const short8*)&bufQ[(16*wq + col)*LS + 8*qd];
        short8 ax1 = *(const short8*)&bufQ[(16*wq + col)*LS + 32 + 8*qd];
        #pragma unroll
        for (int jn = 0; jn < 4; jn++){
            int c = 16*jn + col;
            short8 wv0 = *(const short8*)&kvwb[(64 + c)*64 + 8*qd];
            short8 wv1 = *(const short8*)&kvwb[(64 + c)*64 + 32 + 8*qd];
            float4v acc = zf;
            acc = MFMA(ax0, wv0, acc);
            acc = MFMA(ax1, wv1, acc);
            float bv = kvb[64 + c];
            short4v pk;
            #pragma unroll
            for (int r = 0; r < 4; r++) pk[r] = f2bs(acc[r] + bv);
            *(short4v*)&bufV[c*LS + 16*wq + 4*qd] = pk;
        }
        short8 a0 = *(const short8*)&kvwb[(16*wq + col)*64 + 8*qd];
        short8 a1 = *(const short8*)&kvwb[(16*wq + col)*64 + 32 + 8*qd];
        float kbr[4];
        #pragma unroll
        for (int r = 0; r < 4; r++) kbr[r] = kvb[16*wq + 4*qd + r];
        #pragma unroll
        for (int jn = 0; jn < 4; jn++){
            int t = 16*jn + col;
            short8 bx0 = *(const short8*)&bufQ[t*LS + 8*qd];
            short8 bx1 = *(const short8*)&bufQ[t*LS + 32 + 8*qd];
            float4v acc = zf;
            acc = MFMA(a0, bx0, acc);
            acc = MFMA(a1, bx1, acc);
            short4v pk;
            #pragma unroll
            for (int r = 0; r < 4; r++) pk[r] = f2bs(acc[r] + kbr[r]);
            *(short4v*)&bufK[t*LS + 16*wq + 4*qd] = pk;
        }
    }
    __syncthreads();

    // ---- P3: Q from X1w (bufA) -> bufQ (X2w dead); capture X1w residual ----
    {
        short8 a0 = *(const short8*)&qwb[(16*wq + col)*64 + 8*qd];
        short8 a1 = *(const short8*)&qwb[(16*wq + col)*64 + 32 + 8*qd];
        float qbr[4];
        #pragma unroll
        for (int r = 0; r < 4; r++) qbr[r] = qb[16*wq + 4*qd + r];
        #pragma unroll
        for (int jn = 0; jn < 4; jn++){
            int t = 16*jn + col;
            short8 bx0 = *(const short8*)&bufA[t*LS + 8*qd];
            short8 bx1 = *(const short8*)&bufA[t*LS + 32 + 8*qd];
            float4v acc = zf;
            acc = MFMA(a0, bx0, acc);
            acc = MFMA(a1, bx1, acc);
            short4v pk;
            #pragma unroll
            for (int r = 0; r < 4; r++) pk[r] = f2bs((acc[r] + qbr[r]) * 0.25f);
            *(short4v*)&bufQ[t*LS + 16*wq + 4*qd] = pk;
        }
    }
    short4v xreg[4];
    #pragma unroll
    for (int h = 0; h < 4; h++){
        short4v xr;
        #pragma unroll
        for (int r = 0; r < 4; r++)
            xr[r] = bufA[(16*wq + 4*qd + r)*LS + 16*h + col];
        xreg[h] = xr;
    }
    __syncthreads();

    int idx_t[4][4];
    {
        int t = 16*wq + col, ty = t >> 3, tx = t & 7;
        #pragma unroll
        for (int jn = 0; jn < 4; jn++)
            #pragma unroll
            for (int r = 0; r < 4; r++){
                int u = 16*jn + 4*qd + r;
                idx_t[jn][r] = (ty - (u>>3) + 7)*15 + (tx - (u&7) + 7);
            }
    }

    // ---- head loop: S^T -> thread-local softmax -> P (wave-private) -> PV -> Y/Y^T ----
    for (int h = 0; h < 4; h++){
        short8 bq = *(const short8*)&bufQ[(16*wq + col)*LS + h*16 + (qd & 1)*8];
        float pr[4][4];
        #pragma unroll
        for (int jn = 0; jn < 4; jn++){
            short8 ak = *(const short8*)&bufK[(16*jn + col)*LS + h*16 + (qd & 1)*8];
            if (qd >= 2) ak = zero8;
            float4v acc = MFMA(ak, bq, zf);
            #pragma unroll
            for (int r = 0; r < 4; r++)
                pr[jn][r] = acc[r] + rpb_lds[idx_t[jn][r]*4 + h];
        }
        float m = pr[0][0];
        #pragma unroll
        for (int jn = 0; jn < 4; jn++)
            #pragma unroll
            for (int r = 0; r < 4; r++) m = fmaxf(m, pr[jn][r]);
        m = fmaxf(m, __shfl_xor(m, 16));
        m = fmaxf(m, __shfl_xor(m, 32));
        float s = 0.f;
        #pragma unroll
        for (int jn = 0; jn < 4; jn++)
            #pragma unroll
            for (int r = 0; r < 4; r++){ pr[jn][r] = __expf(pr[jn][r] - m); s += pr[jn][r]; }
        s += __shfl_xor(s, 16);
        s += __shfl_xor(s, 32);
        float rc = 1.f / s;
        #pragma unroll
        for (int jn = 0; jn < 4; jn++){
            short4v pk;
            #pragma unroll
            for (int r = 0; r < 4; r++) pk[r] = f2bs(pr[jn][r] * rc);
            *(short4v*)&bufA[(16*wq + col)*LS + 16*jn + 4*qd] = pk;
        }
        short8 ap0 = *(const short8*)&bufA[(16*wq + col)*LS + 8*qd];
        short8 ap1 = *(const short8*)&bufA[(16*wq + col)*LS + 32 + 8*qd];
        short8 bv0 = *(const short8*)&bufV[(h*16 + col)*LS + 8*qd];
        short8 bv1 = *(const short8*)&bufV[(h*16 + col)*LS + 32 + 8*qd];
        float4v acc_o = zf;
        acc_o = MFMA(ap0, bv0, acc_o);
        acc_o = MFMA(ap1, bv1, acc_o);
        __syncthreads();
        short4v ot;
        #pragma unroll
        for (int r = 0; r < 4; r++) ot[r] = f2bs(acc_o[r]);
        *(short4v*)&bufV[(h*16 + col)*LS + 16*wq + 4*qd] = ot;   // Y^T
        #pragma unroll
        for (int r = 0; r < 4; r++)
            bufK[(16*wq + 4*qd + r)*LS + h*16 + col] = ot[r];    // Y
    }
    __syncthreads();

    // ---- energy = Y Y^T (16x16, K=256) ----
    {
        float4v acc_e = zf;
        #pragma unroll
        for (int h = 0; h < 4; h++){
            short8 f0 = *(const short8*)&bufV[(h*16 + col)*LS + 8*qd];
            short8 f1 = *(const short8*)&bufV[(h*16 + col)*LS + 32 + 8*qd];
            acc_e = MFMA(f0, f0, acc_e);
            acc_e = MFMA(f1, f1, acc_e);
        }
        if (wq == 0){
            #pragma unroll
            for (int r = 0; r < 4; r++) energyS[(4*qd + r)*16 + col] = acc_e[r];
        }
    }
    __syncthreads();
    if (tid < 16){
        int i = tid; float m = -1e30f;
        for (int j = 0; j < 16; j++) m = fmaxf(m, energyS[i*16 + j]);
        float s = 0.f; float e[16];
        for (int j = 0; j < 16; j++){ e[j] = __expf(energyS[i*16 + j] - m); s += e[j]; }
        float rc = 1.f / s;
        for (int j = 0; j < 16; j++) soft_bf[i*32 + j] = f2bs(e[j] * rc);
        for (int j = 0; j < 16; j++) soft_bf[i*32 + 16 + j] = 0;
    }
    __syncthreads();

    // ---- lam + assemble XO -> bufK (overwrite Y slots, wave-private rows) ----
    {
        float gam = gammap[0];
        short8 asf = *(const short8*)&soft_bf[col*32 + 8*qd];
        #pragma unroll
        for (int h = 0; h < 4; h++){
            short8 ay = *(const short8*)&bufK[(16*wq + col)*LS + 16*h + (qd & 1)*8];
            float4v acc = MFMA(ay, asf, zf);
            short4v xv = xreg[h];
            #pragma unroll
            for (int r = 0; r < 4; r++){
                int ro = (16*wq + 4*qd + r)*LS + 16*h + col;
                float ot = bs2f(bufK[ro]);
                float qv = bs2f(bufQ[ro]);
                float xo = gam*acc[r] + ot + qv + bs2f(xv[r]);
                bufK[ro] = f2bs(xo);
            }
        }
    }
    __syncthreads();

    // ---- proj: C[c][t] -> XOf[t*66+c] packed f2 ----
    {
        short8 a0 = *(const short8*)&pwb[(16*wq + col)*64 + 8*qd];
        short8 a1 = *(const short8*)&pwb[(16*wq + col)*64 + 32 + 8*qd];
        float pbr[4];
        #pragma unroll
        for (int r = 0; r < 4; r++) pbr[r] = pb[16*wq + 4*qd + r];
        #pragma unroll
        for (int jn = 0; jn < 4; jn++){
            int t = 16*jn + col;
            short8 bx0 = *(const short8*)&bufK[t*LS + 8*qd];
            short8 bx1 = *(const short8*)&bufK[t*LS + 32 + 8*qd];
            float4v acc = zf;
            acc = MFMA(a0, bx0, acc);
            acc = MFMA(a1, bx1, acc);
            float2v w0 = {acc[0]+pbr[0], acc[1]+pbr[1]};
            float2v w1 = {acc[2]+pbr[2], acc[3]+pbr[3]};
            *(float2v*)&XOf[t*66 + 16*wq + 4*qd]     = w0;
            *(float2v*)&XOf[t*66 + 16*wq + 4*qd + 2] = w1;
        }
    }
    __syncthreads();

    // ================= fused channel-MLP =================
    {
        int p = tid & 63, qg = tid >> 6;
        float s = 0.f, ss = 0.f;
        #pragma unroll
        for (int j = 0; j < 8; j++){
            float2v v = *(const float2v*)&XOf[p*66 + qg*16 + 2*j];
            s += v[0]+v[1]; ss += v[0]*v[0] + v[1]*v[1];
        }
        sumS[qg*64 + p] = s; sqS[qg*64 + p] = ss;
    }
    __syncthreads();
    if (tid < 64){
        float s  = sumS[tid] + sumS[64+tid] + sumS[128+tid] + sumS[192+tid];
        float ss = sqS[tid]  + sqS[64+tid]  + sqS[128+tid]  + sqS[192+tid];
        float m = s * (1.f/64.f);
        float var = ss * (1.f/64.f) - m*m;
        muS[tid] = m; rinvS[tid] = rsqrtf(var + EPS);
    }
    __syncthreads();
    {
        int p = tid & 63, qg = tid >> 6;
        float m = muS[p], rv = rinvS[p];
        short8 o8[2];
        #pragma unroll
        for (int k = 0; k < 2; k++)
            #pragma unroll
            for (int j = 0; j < 8; j++){
                int c = qg*16 + k*8 + j;
                o8[k][j] = f2bs((XOf[p*66 + c] - m) * rv * n2g[c] + n2b[c]);
            }
        *(short8*)&tnb[p*LS + qg*16]     = o8[0];
        *(short8*)&tnb[p*LS + qg*16 + 8] = o8[1];
    }
    __syncthreads();
    // GEMM1: C[j][t]; h1b[t][j] packed
    {
        short8 a0 = *(const short8*)&f1b[(16*wq + col)*64 + 8*qd];
        short8 a1 = *(const short8*)&f1b[(16*wq + col)*64 + 32 + 8*qd];
        float fbr[4];
        #pragma unroll
        for (int r = 0; r < 4; r++) fbr[r] = fb1[16*wq + 4*qd + r];
        #pragma unroll
        for (int jn = 0; jn < 4; jn++){
            int t = 16*jn + col;
            short8 bx0 = *(const short8*)&tnb[t*LS + 8*qd];
            short8 bx1 = *(const short8*)&tnb[t*LS + 32 + 8*qd];
            float4v acc = zf;
            acc = MFMA(a0, bx0, acc);
            acc = MFMA(a1, bx1, acc);
            short4v pk;
            #pragma unroll
            for (int r = 0; r < 4; r++) pk[r] = f2bs(gelu_exact(acc[r] + fbr[r]));
            *(short4v*)&h1b[t*LS + 16*wq + 4*qd] = pk;
        }
    }
    __syncthreads();
    // GEMM2: out = xo + h1 @ W2^T + fb2 -> global planar fp32
    {
        short8 a0 = *(const short8*)&h1b[(16*wq + col)*LS + 8*qd];
        short8 a1 = *(const short8*)&h1b[(16*wq + col)*LS + 32 + 8*qd];
        #pragma unroll
        for (int jn = 0; jn < 4; jn++){
            int c2 = 16*jn + col;
            short8 f0 = *(const short8*)&f2b[c2*64 + 8*qd];
            short8 f1 = *(const short8*)&f2b[c2*64 + 32 + 8*qd];
            float4v acc = zf;
            acc = MFMA(a0, f0, acc);
            acc = MFMA(a1, f1, acc);
            float bv = fb2[c2];
            float4v ov;
            #pragma unroll
            for (int r = 0; r < 4; r++)
                ov[r] = acc[r] + bv + XOf[(16*wq + 4*qd + r)*66 + c2];
            int t0 = 16*wq + 4*qd;
            *(float4v*)(outp + base + (size_t)c2*HW + HWOF(t0)) = ov;
        }
    }
    #undef HWOF
}

extern "C" void kernel_launch(void* const* d_in, const int* in_sizes, int n_in,
                              void* d_out, int out_size, void* d_ws, size_t ws_size,
                              hipStream_t stream){
    const float* x        = (const float*)d_in[0];
    const float* l1_g1    = (const float*)d_in[1];
    const float* l1_b1    = (const float*)d_in[2];
    const float* l1_cw    = (const float*)d_in[3];
    const float* l1_cb    = (const float*)d_in[4];
    const float* l1_g2    = (const float*)d_in[5];
    const float* l1_b2    = (const float*)d_in[6];
    const float* l2_g1    = (const float*)d_in[7];
    const float* l2_b1    = (const float*)d_in[8];
    const float* l2_cw    = (const float*)d_in[9];
    const float* l2_cb    = (const float*)d_in[10];
    const float* l2_g2    = (const float*)d_in[11];
    const float* l2_b2    = (const float*)d_in[12];
    const float* pos1     = (const float*)d_in[13];
    const float* pos2     = (const float*)d_in[14];
    const float* q_w      = (const float*)d_in[15];
    const float* q_b      = (const float*)d_in[16];
    const float* kv_w     = (const float*)d_in[17];
    const float* kv_b     = (const float*)d_in[18];
    const float* rpb      = (const float*)d_in[19];
    const float* gamma    = (const float*)d_in[20];
    const float* proj_w   = (const float*)d_in[21];
    const float* proj_b   = (const float*)d_in[22];
    const float* norm2_g  = (const float*)d_in[23];
    const float* norm2_b  = (const float*)d_in[24];
    const float* fc1_w    = (const float*)d_in[25];
    const float* fc1_b    = (const float*)d_in[26];
    const float* fc2_w    = (const float*)d_in[27];
    const float* fc2_b    = (const float*)d_in[28];

    float* out = (float*)d_out;                 // final output only (written once)

    float* partS = (float*)d_ws;                // 2048*64 floats (512 KB)
    float* partQ = partS + (size_t)2048*64;     // 512 KB
    float* mu1   = partQ + (size_t)2048*64;     // 1024
    float* rinv1 = mu1 + 1024;                  // 1024
    float* mu2   = rinv1 + 1024;                // 2048
    float* rinv2 = mu2 + 2048;                  // 2048
    float* rowsumG = rinv2 + 2048;              // 128
    short* wbuf  = (short*)(rowsumG + 128);     // 32768 shorts

    k_pre  <<<1033, 256, 0, stream>>>(x, mu1, rinv1,
                                      l1_cw, l2_cw, q_w, kv_w, proj_w, fc1_w, fc2_w,
                                      wbuf, rowsumG);
    k_conv <<<1024, 256, 0, stream>>>(x, mu1, rinv1,
                                      l1_g1, l1_b1, l1_cb,
                                      l2_g1, l2_b1, l2_cb,
                                      wbuf, rowsumG,
                                      partS, partQ);
    k_fin  <<<512, 256, 0, stream>>>(partS, partQ, mu2, rinv2);
    k_attn <<<4096, 256, 0, stream>>>(x, out, mu1, rinv1, rowsumG,
                                      l1_cb, l2_cb,
                                      l1_g1, l1_b1, l2_g1, l2_b1,
                                      mu2, rinv2,
                                      l1_g2, l1_b2, l2_g2, l2_b2,
                                      pos1, pos2, wbuf, q_b, kv_b,
                                      rpb, gamma, proj_b,
                                      norm2_g, norm2_b, fc1_b, fc2_b);
}